// Round 14
// baseline (1105.684 us; speedup 1.0000x reference)
//
#include <hip/hip_runtime.h>

typedef unsigned short u16;
typedef __attribute__((ext_vector_type(8))) __bf16 bf16x8;
typedef __attribute__((ext_vector_type(4))) float float4v;
typedef __attribute__((ext_vector_type(4))) u16 ushort4v;
typedef __attribute__((ext_vector_type(4))) unsigned int uint4v;

#define VOCAB 36906
#define VPAD  36928   // 577*64
#define WDP   320     // K-pad of 300 for emb GEMM
#define HID   200
#define NG    800     // 4H
#define NGP   832     // 13*64
#define KP    224     // 7*32 (H padded)
#define SS    256
#define ROWS  4       // LSTM rows per block (128 blocks)
#define HS    232     // hbuf row stride (u16)
#define WLS   228     // wlds row stride (u16)
#define NREG  5       // AGPR-resident W_hh tiles per wave (tiles w+8i -> 0..39)
#define NLDS  10      // LDS-resident tiles 40..49

__device__ __forceinline__ float b2f(u16 u) {
  union { unsigned int i; float f; } c; c.i = ((unsigned int)u) << 16; return c.f;
}
__device__ __forceinline__ u16 f2b(float f) {
  union { float f; unsigned int i; } c; c.f = f;
  unsigned int u = c.i;
  u += 0x7fffu + ((u >> 16) & 1u);
  return (u16)(u >> 16);
}
__device__ __forceinline__ float sigm(float x) { return 1.f / (1.f + __expf(-x)); }
__device__ __forceinline__ float tanh_f(float x) {
  float e = __expf(2.f * x);
  return 1.f - 2.f / (e + 1.f);
}

// ---------------- packing ----------------

__global__ void conv_emb(const float* __restrict__ emb, u16* __restrict__ out) {
  for (long long idx = (long long)blockIdx.x * 256 + threadIdx.x;
       idx < (long long)VPAD * WDP; idx += (long long)gridDim.x * 256) {
    int v = (int)(idx / WDP), k = (int)(idx % WDP);
    float val = (v < VOCAB && k < 300) ? emb[(long long)v * 300 + k] : 0.f;
    out[idx] = f2b(val);
  }
}

// W_ih rows permuted to interleaved gate order n' = 4*j + gate, K padded to 320
__global__ void conv_wih(const float* __restrict__ W, u16* __restrict__ out) {
  int idx = blockIdx.x * 256 + threadIdx.x;
  if (idx < NGP * WDP) {
    int n = idx / WDP, k = idx % WDP;
    float v = 0.f;
    if (n < NG && k < 300) { int gt = n & 3, j = n >> 2; v = W[(gt * HID + j) * 300 + k]; }
    out[idx] = f2b(v);
  }
}

__global__ void conv_whh(const float* __restrict__ W, u16* __restrict__ out) {
  int idx = blockIdx.x * 256 + threadIdx.x;
  if (idx < NG * KP) {
    int n = idx / KP, k = idx % KP;
    int gt = n & 3, j = n >> 2;
    float v = (k < HID) ? W[(gt * HID + j) * HID + k] : 0.f;
    out[idx] = f2b(v);
  }
}

__global__ void conv_bias(const float* __restrict__ bi, const float* __restrict__ bh,
                          float* __restrict__ out) {
  int n = blockIdx.x * 256 + threadIdx.x;
  if (n < NGP) {
    float v = 0.f;
    if (n < NG) { int gt = n & 3, j = n >> 2; v = bi[gt * HID + j] + bh[gt * HID + j]; }
    out[n] = v;
  }
}

// ---------------- E2 = emb @ W_ih'^T + bias  (NT GEMM, bf16 out) ----------------

__global__ __launch_bounds__(256, 2) void gemm_e2(
    const u16* __restrict__ A, const u16* __restrict__ B, u16* __restrict__ C,
    const float* __restrict__ bias) {
  __shared__ __align__(16) u16 La[64 * 40];
  __shared__ __align__(16) u16 Lb[64 * 40];
  const int m0 = blockIdx.x * 64, n0 = blockIdx.y * 64;
  const int tid = threadIdx.x, l = tid & 63, w = tid >> 6;
  const int wr = w >> 1, wc = w & 1;
  const int sr = tid >> 2, sc = (tid & 3) * 8;
  float4v acc[2][2] = {};
  for (int k0 = 0; k0 < WDP; k0 += 32) {
    uint4v qa = *(const uint4v*)&A[(long long)(m0 + sr) * WDP + k0 + sc];
    uint4v qb = *(const uint4v*)&B[(long long)(n0 + sr) * WDP + k0 + sc];
    __syncthreads();
    *(uint4v*)&La[sr * 40 + sc] = qa;
    *(uint4v*)&Lb[sr * 40 + sc] = qb;
    __syncthreads();
    bf16x8 af[2], bfr[2];
#pragma unroll
    for (int mt = 0; mt < 2; ++mt)
      af[mt] = *(const bf16x8*)&La[(wr * 32 + mt * 16 + (l & 15)) * 40 + (l >> 4) * 8];
#pragma unroll
    for (int nt = 0; nt < 2; ++nt)
      bfr[nt] = *(const bf16x8*)&Lb[(wc * 32 + nt * 16 + (l & 15)) * 40 + (l >> 4) * 8];
#pragma unroll
    for (int mt = 0; mt < 2; ++mt)
#pragma unroll
      for (int nt = 0; nt < 2; ++nt)
        acc[mt][nt] = __builtin_amdgcn_mfma_f32_16x16x32_bf16(af[mt], bfr[nt], acc[mt][nt], 0, 0, 0);
  }
#pragma unroll
  for (int mt = 0; mt < 2; ++mt)
#pragma unroll
    for (int nt = 0; nt < 2; ++nt)
#pragma unroll
      for (int j = 0; j < 4; ++j) {
        int row = m0 + wr * 32 + mt * 16 + (l >> 4) * 4 + j;
        int col = n0 + wc * 32 + nt * 16 + (l & 15);
        if (row < VOCAB && col < NG)
          C[(long long)row * NG + col] = f2b(acc[mt][nt][j] + bias[col]);
      }
}

// ---------------- LSTM: 128 blocks x 4 rows x 512 threads (8 waves) ----------------
// W_hh: 40 tiles AGPR (5/wave, tiles w+8i) + tiles 40..49 LDS.
// Swapped-operand MFMA -> lane (m=l&15, grp=l>>4) holds all 4 gates of unit
// (4*nt+grp) for batch row m: nonlinearity fully IN-REGISTER (act lanes m<ROWS),
// cell state lane-owned, E2 in lane-owned register dbuf. h ping-pong in LDS ->
// ONE barrier per step. hid out: [512 r][256 t][224 h] bf16, coalesced u32 writes.

__global__ __launch_bounds__(512, 2) void lstm_kernel(
    const int* __restrict__ premise, const int* __restrict__ hypothesis,
    const u16* __restrict__ E2, const u16* __restrict__ Whh,
    u16* __restrict__ hid) {
  __shared__ u16 tok[ROWS * 256];                     //   2.0 KB
  __shared__ __align__(16) u16 hb[2][16 * HS];        //  14.5 KB
  __shared__ __align__(16) u16 wlds[NLDS * 16 * WLS]; //  71.3 KB -> ~88 KB total
  const int tid = threadIdx.x;
  const int l = tid & 63, w = tid >> 6;
  const int r0 = blockIdx.x * ROWS;
  const int m = l & 15, grp = l >> 4;
  const bool act = (m < ROWS);

  for (int idx = tid; idx < ROWS * 256; idx += 512) {
    int mm = idx >> 8, tt = idx & 255;
    int row = r0 + mm;
    const int* seq = (row < 256) ? premise : hypothesis;
    tok[idx] = (u16)seq[(row & 255) * 256 + tt];
  }
  for (int idx = tid; idx < 2 * 16 * HS; idx += 512) ((u16*)hb)[idx] = 0;
  // LDS-resident W_hh tiles 40..49
  for (int idx = tid; idx < NLDS * 16 * KP; idx += 512) {
    int slot = idx / (16 * KP), rem = idx % (16 * KP);
    int r = rem / KP, k = rem % KP;
    wlds[(slot * 16 + r) * WLS + k] = Whh[((40 + slot) * 16 + r) * KP + k];
  }

  // AGPR-resident W_hh: wave w owns tiles w+8i, i<NREG (0..39)
  uint4v wf[NREG][7];
#pragma unroll
  for (int i = 0; i < NREG; ++i) {
    int nt = w + 8 * i;
#pragma unroll
    for (int kf = 0; kf < 7; ++kf)
      wf[i][kf] = *(const uint4v*)&Whh[(nt * 16 + (l & 15)) * KP + kf * 32 + (l >> 4) * 8];
  }
#pragma unroll
  for (int i = 0; i < NREG; ++i)
#pragma unroll
    for (int kf = 0; kf < 7; ++kf)
      asm volatile("" : "+a"(wf[i][kf]));

  // lane-owned cell state: slots 0..4 = AGPR tiles, 5 = tile 40+w, 6 = tile 48+w
  float cst[7];
#pragma unroll
  for (int q = 0; q < 7; ++q) cst[q] = 0.f;

  __syncthreads();

  // preload E2(t=0): lane owns units u = 4*(w+8i)+grp, 4*(40+w)+grp, 4*(48+w)+grp
  ushort4v ev[7];
  if (act) {
    long long tk = tok[m * 256];
#pragma unroll
    for (int i = 0; i < NREG; ++i)
      ev[i] = *(const ushort4v*)&E2[tk * NG + 4 * (4 * (w + 8 * i) + grp)];
    ev[5] = *(const ushort4v*)&E2[tk * NG + 4 * (4 * (40 + w) + grp)];
    if (w < 2)
      ev[6] = *(const ushort4v*)&E2[tk * NG + 4 * (4 * (48 + w) + grp)];
  }

  for (int t = 0; t < SS; ++t) {
    const u16* hr = hb[(t & 1) ^ 1];   // h(t-1)
    u16* hw = hb[t & 1];               // h(t)

    // coalesced hid write of h(t-1)
    if (t > 0) {
      const unsigned* hb32 = (const unsigned*)hr;
      unsigned* hid32 = (unsigned*)hid;
      if (tid < ROWS * 112) {
        int m2 = tid / 112, c = tid - 112 * m2;
        hid32[((long long)(r0 + m2) * SS + (t - 1)) * 112 + c] = hb32[m2 * 116 + c];
      }
    }

    // A-fragments (h(t-1))
    bf16x8 af[7];
#pragma unroll
    for (int kf = 0; kf < 7; ++kf)
      af[kf] = *(const bf16x8*)&hr[(l & 15) * HS + kf * 32 + (l >> 4) * 8];

    // prefetch E2(t+1)
    ushort4v evn[7];
    int t2 = (t < SS - 1) ? t + 1 : t;
    if (act) {
      long long tk = tok[m * 256 + t2];
#pragma unroll
      for (int i = 0; i < NREG; ++i)
        evn[i] = *(const ushort4v*)&E2[tk * NG + 4 * (4 * (w + 8 * i) + grp)];
      evn[5] = *(const ushort4v*)&E2[tk * NG + 4 * (4 * (40 + w) + grp)];
      if (w < 2)
        evn[6] = *(const ushort4v*)&E2[tk * NG + 4 * (4 * (48 + w) + grp)];
    }

    // ---- AGPR tiles: 5 interleaved MFMA chains -> in-register gate epilogue ----
    {
      float4v acc[NREG];
#pragma unroll
      for (int i = 0; i < NREG; ++i) acc[i] = float4v{0.f, 0.f, 0.f, 0.f};
      asm volatile("s_nop 1"
                   : "+v"(acc[0]), "+v"(acc[1]), "+v"(acc[2]), "+v"(acc[3]), "+v"(acc[4]));
#pragma unroll
      for (int kf = 0; kf < 7; ++kf)
#pragma unroll
        for (int i = 0; i < NREG; ++i)
          asm volatile("v_mfma_f32_16x16x32_bf16 %0, %1, %2, %0"
                       : "+v"(acc[i])
                       : "a"(wf[i][kf]), "v"(af[kf]));
      asm volatile("s_nop 7\n\ts_nop 7"
                   : "+v"(acc[0]), "+v"(acc[1]), "+v"(acc[2]), "+v"(acc[3]), "+v"(acc[4]));
      if (act) {
#pragma unroll
        for (int i = 0; i < NREG; ++i) {
          int u = 4 * (w + 8 * i) + grp;
          float gi = acc[i][0] + b2f(ev[i].x);
          float gf = acc[i][1] + b2f(ev[i].y);
          float gg = acc[i][2] + b2f(ev[i].z);
          float go = acc[i][3] + b2f(ev[i].w);
          float cn = sigm(gf) * cst[i] + sigm(gi) * tanh_f(gg);
          float hn = sigm(go) * tanh_f(cn);
          cst[i] = cn;
          hw[m * HS + u] = f2b(hn);
        }
      }
    }
    // LDS tile 40+w (all waves)
    {
      float4v a2 = {0.f, 0.f, 0.f, 0.f};
#pragma unroll
      for (int kf = 0; kf < 7; ++kf) {
        bf16x8 bfr = *(const bf16x8*)&wlds[(w * 16 + (l & 15)) * WLS + kf * 32 + (l >> 4) * 8];
        a2 = __builtin_amdgcn_mfma_f32_16x16x32_bf16(bfr, af[kf], a2, 0, 0, 0);
      }
      if (act) {
        int u = 4 * (40 + w) + grp;
        float gi = a2[0] + b2f(ev[5].x);
        float gf = a2[1] + b2f(ev[5].y);
        float gg = a2[2] + b2f(ev[5].z);
        float go = a2[3] + b2f(ev[5].w);
        float cn = sigm(gf) * cst[5] + sigm(gi) * tanh_f(gg);
        float hn = sigm(go) * tanh_f(cn);
        cst[5] = cn;
        hw[m * HS + u] = f2b(hn);
      }
    }
    // LDS tiles 48,49 (waves 0,1)
    if (w < 2) {
      int slot = 8 + w;
      float4v a2 = {0.f, 0.f, 0.f, 0.f};
#pragma unroll
      for (int kf = 0; kf < 7; ++kf) {
        bf16x8 bfr = *(const bf16x8*)&wlds[(slot * 16 + (l & 15)) * WLS + kf * 32 + (l >> 4) * 8];
        a2 = __builtin_amdgcn_mfma_f32_16x16x32_bf16(bfr, af[kf], a2, 0, 0, 0);
      }
      if (act) {
        int u = 4 * (48 + w) + grp;
        float gi = a2[0] + b2f(ev[6].x);
        float gf = a2[1] + b2f(ev[6].y);
        float gg = a2[2] + b2f(ev[6].z);
        float go = a2[3] + b2f(ev[6].w);
        float cn = sigm(gf) * cst[6] + sigm(gi) * tanh_f(gg);
        float hn = sigm(go) * tanh_f(cn);
        cst[6] = cn;
        hw[m * HS + u] = f2b(hn);
      }
    }

#pragma unroll
    for (int i = 0; i < 7; ++i) ev[i] = evn[i];
    __syncthreads();  // h(t) complete; next step reads hw as hr
  }

  // epilogue: write h(255)
  {
    const unsigned* hb32 = (const unsigned*)hb[(SS - 1) & 1];
    unsigned* hid32 = (unsigned*)hid;
    if (tid < ROWS * 112) {
      int m2 = tid / 112, c = tid - 112 * m2;
      hid32[((long long)(r0 + m2) * SS + (SS - 1)) * 112 + c] = hb32[m2 * 116 + c];
    }
  }
}

// ---------------- attn (NT): X[b][i][j] = sum_h Hp[i][h]*Hh[j][h], bf16 out --------

__global__ __launch_bounds__(256, 2) void gemm_attn(const u16* __restrict__ H,
                                                    u16* __restrict__ X) {
  __shared__ __align__(16) u16 La[64 * 40];
  __shared__ __align__(16) u16 Lb[64 * 40];
  const int z = blockIdx.z;
  const u16* A = H + (long long)z * SS * KP;
  const u16* B = H + (long long)(z + 256) * SS * KP;
  u16* C = X + (long long)z * 65536;
  const int m0 = blockIdx.x * 64, n0 = blockIdx.y * 64;
  const int tid = threadIdx.x, l = tid & 63, w = tid >> 6;
  const int wr = w >> 1, wc = w & 1;
  const int sr = tid >> 2, sc = (tid & 3) * 8;
  float4v acc[2][2] = {};
  for (int k0 = 0; k0 < KP; k0 += 32) {
    uint4v qa = *(const uint4v*)&A[(m0 + sr) * KP + k0 + sc];
    uint4v qb = *(const uint4v*)&B[(n0 + sr) * KP + k0 + sc];
    __syncthreads();
    *(uint4v*)&La[sr * 40 + sc] = qa;
    *(uint4v*)&Lb[sr * 40 + sc] = qb;
    __syncthreads();
    bf16x8 af[2], bfr[2];
#pragma unroll
    for (int mt = 0; mt < 2; ++mt)
      af[mt] = *(const bf16x8*)&La[(wr * 32 + mt * 16 + (l & 15)) * 40 + (l >> 4) * 8];
#pragma unroll
    for (int nt = 0; nt < 2; ++nt)
      bfr[nt] = *(const bf16x8*)&Lb[(wc * 32 + nt * 16 + (l & 15)) * 40 + (l >> 4) * 8];
#pragma unroll
    for (int mt = 0; mt < 2; ++mt)
#pragma unroll
      for (int nt = 0; nt < 2; ++nt)
        acc[mt][nt] = __builtin_amdgcn_mfma_f32_16x16x32_bf16(af[mt], bfr[nt], acc[mt][nt], 0, 0, 0);
  }
#pragma unroll
  for (int mt = 0; mt < 2; ++mt)
#pragma unroll
    for (int nt = 0; nt < 2; ++nt)
#pragma unroll
      for (int j = 0; j < 4; ++j) {
        int row = m0 + wr * 32 + mt * 16 + (l >> 4) * 4 + j;
        int col = n0 + wc * 32 + nt * 16 + (l & 15);
        C[row * SS + col] = f2b(acc[mt][nt][j]);
      }
}

// ---------------- softmax stats ----------------

__global__ void rowstats(const u16* __restrict__ X, float* __restrict__ rm,
                         float* __restrict__ ri) {
  int r = blockIdx.x * 4 + (threadIdx.x >> 6);
  int l = threadIdx.x & 63;
  ushort4v q = *(const ushort4v*)(X + (long long)r * 256 + l * 4);
  float v0 = b2f(q.x), v1 = b2f(q.y), v2 = b2f(q.z), v3 = b2f(q.w);
  float m = fmaxf(fmaxf(v0, v1), fmaxf(v2, v3));
#pragma unroll
  for (int off = 32; off; off >>= 1) m = fmaxf(m, __shfl_xor(m, off));
  float s = __expf(v0 - m) + __expf(v1 - m) + __expf(v2 - m) + __expf(v3 - m);
#pragma unroll
  for (int off = 32; off; off >>= 1) s += __shfl_xor(s, off);
  if (l == 0) { rm[r] = m; ri[r] = 1.f / s; }
}

__global__ void colstats(const u16* __restrict__ X, float* __restrict__ cm,
                         float* __restrict__ ci) {
  int b = blockIdx.x, j0 = blockIdx.y * 16;
  int tid = threadIdx.x, jj = tid & 15, iq = tid >> 4;
  const u16* base = X + (long long)b * 65536;
  float v[16];
  float m = -1e30f;
#pragma unroll
  for (int ch = 0; ch < 16; ++ch) {
    v[ch] = b2f(base[(ch * 16 + iq) * 256 + j0 + jj]);
    m = fmaxf(m, v[ch]);
  }
  __shared__ float red[256];
  red[tid] = m; __syncthreads();
#pragma unroll
  for (int off = 128; off >= 16; off >>= 1) {
    if (tid < off) red[tid] = fmaxf(red[tid], red[tid + off]);
    __syncthreads();
  }
  float mm = red[jj]; __syncthreads();
  float s = 0.f;
#pragma unroll
  for (int ch = 0; ch < 16; ++ch) s += __expf(v[ch] - mm);
  red[tid] = s; __syncthreads();
#pragma unroll
  for (int off = 128; off >= 16; off >>= 1) {
    if (tid < off) red[tid] += red[tid + off];
    __syncthreads();
  }
  if (tid < 16) { cm[b * 256 + j0 + tid] = mm; ci[b * 256 + j0 + tid] = 1.f / red[tid]; }
}

// ---------------- PV GEMMs: on-the-fly softmax A, transpose-staged V from hid ------
// TRANSA=0: C[i][h] = sum_j exp(X[i][j]-rm[i])*ri[i] * Hh[j][h]
// TRANSA=1: C[j][h] = sum_i exp(X[i][j]-cm[j])*ci[j] * Hp[i][h]
// pmax[(z*4+blockIdx.x)*256 + col] = max over the tile's 64 rows

template <int TRANSA>
__global__ __launch_bounds__(256, 2) void gemm_pv(
    const u16* __restrict__ X, const u16* __restrict__ H,
    const float* __restrict__ sm, const float* __restrict__ sinv,
    float* __restrict__ pmax) {
  __shared__ __align__(16) u16 La[64 * 40];
  __shared__ __align__(16) u16 Lb[64 * 40];
  __shared__ float red[8][64];
  const int z = blockIdx.z;
  const u16* Xz = X + (long long)z * 65536;
  const u16* B = H + (long long)(TRANSA ? z : z + 256) * SS * KP;
  const int m0 = blockIdx.x * 64, n0 = blockIdx.y * 64;
  const int tid = threadIdx.x, l = tid & 63, w = tid >> 6;
  const int wr = w >> 1, wc = w & 1;
  const int sr = tid >> 2, sc = (tid & 3) * 8;
  const int sr2 = tid >> 3, sc2 = (tid & 7) * 8;

  float m_s0 = 0.f, i_s0 = 0.f;
  float mj[8], ij[8];
  if (TRANSA == 0) {
    m_s0 = sm[z * 256 + m0 + sr];
    i_s0 = sinv[z * 256 + m0 + sr];
  } else {
#pragma unroll
    for (int e = 0; e < 8; ++e) {
      mj[e] = sm[z * 256 + m0 + sc2 + e];
      ij[e] = sinv[z * 256 + m0 + sc2 + e];
    }
  }

  float4v acc[2][2] = {};
  for (int k0 = 0; k0 < SS; k0 += 32) {
    union { uint4v v; u16 s[8]; } ua, ub;
    if (TRANSA == 0)
      ua.v = *(const uint4v*)&Xz[(m0 + sr) * SS + k0 + sc];
    else
      ua.v = *(const uint4v*)&Xz[(k0 + sr2) * SS + m0 + sc2];
    ub.v = *(const uint4v*)&B[(long long)(k0 + sr2) * KP + n0 + sc2];
    __syncthreads();
    if (TRANSA == 0) {
      u16 pa[8];
#pragma unroll
      for (int e = 0; e < 8; ++e)
        pa[e] = f2b(__expf(b2f(ua.s[e]) - m_s0) * i_s0);
      uint4v pk;
      pk.x = (unsigned)pa[0] | ((unsigned)pa[1] << 16);
      pk.y = (unsigned)pa[2] | ((unsigned)pa[3] << 16);
      pk.z = (unsigned)pa[4] | ((unsigned)pa[5] << 16);
      pk.w = (unsigned)pa[6] | ((unsigned)pa[7] << 16);
      *(uint4v*)&La[sr * 40 + sc] = pk;
    } else {
#pragma unroll
      for (int e = 0; e < 8; ++e)
        La[(sc2 + e) * 40 + sr2] = f2b(__expf(b2f(ua.s[e]) - mj[e]) * ij[e]);
    }
    // V staged transposed: Lb[hcol][k] from hid rows (k) x hcols
#pragma unroll
    for (int e = 0; e < 8; ++e)
      Lb[(sc2 + e) * 40 + sr2] = (n0 + sc2 + e < KP) ? ub.s[e] : (u16)0;
    __syncthreads();
    bf16x8 af[2], bfr[2];
#pragma unroll
    for (int mt = 0; mt < 2; ++mt)
      af[mt] = *(const bf16x8*)&La[(wr * 32 + mt * 16 + (l & 15)) * 40 + (l >> 4) * 8];
#pragma unroll
    for (int nt = 0; nt < 2; ++nt)
      bfr[nt] = *(const bf16x8*)&Lb[(wc * 32 + nt * 16 + (l & 15)) * 40 + (l >> 4) * 8];
#pragma unroll
    for (int mt = 0; mt < 2; ++mt)
#pragma unroll
      for (int nt = 0; nt < 2; ++nt)
        acc[mt][nt] = __builtin_amdgcn_mfma_f32_16x16x32_bf16(af[mt], bfr[nt], acc[mt][nt], 0, 0, 0);
  }
  // fused max over the 64 tile rows
#pragma unroll
  for (int nt = 0; nt < 2; ++nt) {
    float v = -1e30f;
#pragma unroll
    for (int mt = 0; mt < 2; ++mt)
#pragma unroll
      for (int j = 0; j < 4; ++j) v = fmaxf(v, acc[mt][nt][j]);
    red[wr * 4 + (l >> 4)][wc * 32 + nt * 16 + (l & 15)] = v;
  }
  __syncthreads();
  if (tid < 64) {
    float m = red[0][tid];
#pragma unroll
    for (int g = 1; g < 8; ++g) m = fmaxf(m, red[g][tid]);
    pmax[((long long)z * 4 + blockIdx.x) * 256 + n0 + tid] = m;
  }
}

__global__ void maxfinal(const float* __restrict__ p1, const float* __restrict__ p2,
                         float* __restrict__ hq, float* __restrict__ hs) {
  int b = blockIdx.x, h = threadIdx.x;
  if (h < HID) {
    float m1 = -1e30f, m2 = -1e30f;
#pragma unroll
    for (int x = 0; x < 4; ++x) {
      m1 = fmaxf(m1, p1[(b * 4 + x) * 256 + h]);
      m2 = fmaxf(m2, p2[(b * 4 + x) * 256 + h]);
    }
    hq[b * HID + h] = m1;
    hs[b * HID + h] = m2;
  }
}

// ---------------- head: feat -> logits -> log_softmax (f32 out) ----------------

__global__ void final_k(const float* __restrict__ hq, const float* __restrict__ hs,
                        const float* __restrict__ Wl, const float* __restrict__ bl,
                        float* __restrict__ out) {
  int b = blockIdx.x, t = threadIdx.x;
  float a0 = 0.f, a1v = 0.f, a2v = 0.f;
  for (int hp = t; hp < 800; hp += 256) {
    int part = hp / 200, u = hp - part * 200;
    float q = hq[b * HID + u], s = hs[b * HID + u];
    float f = (part == 0) ? q : (part == 1) ? s : (part == 2) ? (q - s) : (q * s);
    a0 += f * Wl[hp]; a1v += f * Wl[800 + hp]; a2v += f * Wl[1600 + hp];
  }
#pragma unroll
  for (int off = 32; off; off >>= 1) {
    a0 += __shfl_xor(a0, off); a1v += __shfl_xor(a1v, off); a2v += __shfl_xor(a2v, off);
  }
  __shared__ float rr[12];
  int w = t >> 6;
  if ((t & 63) == 0) { rr[w] = a0; rr[4 + w] = a1v; rr[8 + w] = a2v; }
  __syncthreads();
  if (t == 0) {
    float l0 = rr[0] + rr[1] + rr[2] + rr[3] + bl[0];
    float l1 = rr[4] + rr[5] + rr[6] + rr[7] + bl[1];
    float l2 = rr[8] + rr[9] + rr[10] + rr[11] + bl[2];
    float mm = fmaxf(l0, fmaxf(l1, l2));
    float lse = mm + __logf(__expf(l0 - mm) + __expf(l1 - mm) + __expf(l2 - mm));
    out[b * 3 + 0] = l0 - lse;
    out[b * 3 + 1] = l1 - lse;
    out[b * 3 + 2] = l2 - lse;
  }
}

// ---------------- host ----------------

extern "C" void kernel_launch(void* const* d_in, const int* in_sizes, int n_in,
                              void* d_out, int out_size, void* d_ws, size_t ws_size,
                              hipStream_t stream) {
  const int* premise = (const int*)d_in[0];
  const int* hypothesis = (const int*)d_in[1];
  const float* emb = (const float*)d_in[2];
  const float* W_ih = (const float*)d_in[3];
  const float* W_hh = (const float*)d_in[4];
  const float* b_ih = (const float*)d_in[5];
  const float* b_hh = (const float*)d_in[6];
  const float* W_last = (const float*)d_in[7];
  const float* b_last = (const float*)d_in[8];
  float* out = (float*)d_out;

  char* ws = (char*)d_ws;
  // layout (bytes), peak = 118,664,064 (~113 MB)
  const size_t O_hid  = 0;          // [512][256][224] bf16 = 58,720,256
  const size_t O_embB = 0;          // [36928][320] bf16 (dead before lstm writes hid)
  const size_t O_E2   = 58720256;   // [36906][800] bf16 = 59,049,600 (dead after LSTM)
  const size_t O_X    = 58720256;   // [256][256][256] bf16 = 33,554,432 (overlays dead E2)
  const size_t O_rm   = 92274688;   // 65536 f32 (overlays dead E2 tail)
  const size_t O_ri   = 92536832;
  const size_t O_cm   = 92798976;
  const size_t O_ci   = 93061120;
  const size_t O_p1   = 93323264;   // [256][4][256] f32
  const size_t O_p2   = 94371840;
  const size_t O_hq   = 95420416;   // [256][200] f32
  const size_t O_hs   = 95625216;
  const size_t O_whh  = 117769856;  // [800][224] bf16 (live through LSTM, after E2 end)
  const size_t O_wih  = 118128256;  // [832][320] bf16
  const size_t O_bias = 118660736;  // 832 f32 -> end 118,664,064

  u16* hid  = (u16*)(ws + O_hid);
  u16* embB = (u16*)(ws + O_embB);
  u16* E2   = (u16*)(ws + O_E2);
  u16* X    = (u16*)(ws + O_X);
  float* rm = (float*)(ws + O_rm);
  float* ri = (float*)(ws + O_ri);
  float* cm = (float*)(ws + O_cm);
  float* ci = (float*)(ws + O_ci);
  float* p1 = (float*)(ws + O_p1);
  float* p2 = (float*)(ws + O_p2);
  float* hq = (float*)(ws + O_hq);
  float* hs = (float*)(ws + O_hs);
  u16* whhB = (u16*)(ws + O_whh);
  u16* wihB = (u16*)(ws + O_wih);
  float* biasP = (float*)(ws + O_bias);

  conv_emb<<<4096, 256, 0, stream>>>(emb, embB);
  conv_wih<<<(NGP * WDP + 255) / 256, 256, 0, stream>>>(W_ih, wihB);
  conv_whh<<<(NG * KP + 255) / 256, 256, 0, stream>>>(W_hh, whhB);
  conv_bias<<<4, 256, 0, stream>>>(b_ih, b_hh, biasP);

  gemm_e2<<<dim3(VPAD / 64, NGP / 64), 256, 0, stream>>>(embB, wihB, E2, biasP);

  lstm_kernel<<<128, 512, 0, stream>>>(premise, hypothesis, E2, whhB, hid);

  gemm_attn<<<dim3(4, 4, 256), 256, 0, stream>>>(hid, X);

  rowstats<<<16384, 256, 0, stream>>>(X, rm, ri);
  colstats<<<dim3(256, 16), 256, 0, stream>>>(X, cm, ci);

  gemm_pv<0><<<dim3(4, 4, 256), 256, 0, stream>>>(X, hid, rm, ri, p1);
  gemm_pv<1><<<dim3(4, 4, 256), 256, 0, stream>>>(X, hid, cm, ci, p2);

  maxfinal<<<256, 256, 0, stream>>>(p1, p2, hq, hs);
  final_k<<<256, 256, 0, stream>>>(hq, hs, W_last, b_last, out);
}

// Round 15
// 793.688 us; speedup vs baseline: 1.3931x; 1.3931x over previous
//
#include <hip/hip_runtime.h>

typedef unsigned short u16;
typedef __attribute__((ext_vector_type(8))) __bf16 bf16x8;
typedef __attribute__((ext_vector_type(4))) float float4v;
typedef __attribute__((ext_vector_type(4))) u16 ushort4v;
typedef __attribute__((ext_vector_type(4))) unsigned int uint4v;

#define VOCAB 36906
#define VPAD  36928   // 577*64
#define WDP   320     // K-pad of 300 for emb GEMM
#define HID   200
#define NG    800     // 4H
#define NGP   832     // 13*64
#define KP    224     // 7*32 (H padded)
#define SS    256
#define ROWS  4       // LSTM rows per block (128 blocks)
#define HS    232     // hbuf row stride (u16)
#define GSF   804     // gbufF row stride (f32)
#define WLS   228     // wlds row stride (u16)
#define NREG  5       // AGPR-resident W_hh tiles per wave (tiles w+8i -> 0..39)
#define NLDS  10      // LDS-resident tiles 40..49

__device__ __forceinline__ float b2f(u16 u) {
  union { unsigned int i; float f; } c; c.i = ((unsigned int)u) << 16; return c.f;
}
__device__ __forceinline__ u16 f2b(float f) {
  union { float f; unsigned int i; } c; c.f = f;
  unsigned int u = c.i;
  u += 0x7fffu + ((u >> 16) & 1u);
  return (u16)(u >> 16);
}
__device__ __forceinline__ float sigm(float x) { return 1.f / (1.f + __expf(-x)); }
__device__ __forceinline__ float tanh_f(float x) {
  float e = __expf(2.f * x);
  return 1.f - 2.f / (e + 1.f);
}

// ---------------- packing: W_ih (permuted, K-pad 320) + W_hh (permuted, K-pad 224)
// ---------------- + bias, one kernel, three flat regions ----------------

#define R0N (NGP * WDP)
#define R1N (NG * KP)
#define R2N (NGP)

__global__ void conv_pack(const float* __restrict__ Wih, const float* __restrict__ Whh,
                          const float* __restrict__ bi, const float* __restrict__ bh,
                          u16* __restrict__ wihB, u16* __restrict__ whhB,
                          float* __restrict__ biasP) {
  int idx = blockIdx.x * 256 + threadIdx.x;
  if (idx < R0N) {
    int n = idx / WDP, k = idx % WDP;
    float v = 0.f;
    if (n < NG && k < 300) { int gt = n & 3, j = n >> 2; v = Wih[(gt * HID + j) * 300 + k]; }
    wihB[idx] = f2b(v);
  } else if (idx < R0N + R1N) {
    int r = idx - R0N;
    int n = r / KP, k = r % KP;
    int gt = n & 3, j = n >> 2;
    float v = (k < HID) ? Whh[(gt * HID + j) * HID + k] : 0.f;
    whhB[r] = f2b(v);
  } else if (idx < R0N + R1N + R2N) {
    int n = idx - R0N - R1N;
    float v = 0.f;
    if (n < NG) { int gt = n & 3, j = n >> 2; v = bi[gt * HID + j] + bh[gt * HID + j]; }
    biasP[n] = v;
  }
}

// ---------------- E2 = emb @ W_ih'^T + bias  (NT GEMM, f32 A fused-convert) --------

__global__ __launch_bounds__(256, 2) void gemm_e2(
    const float* __restrict__ emb, const u16* __restrict__ B, u16* __restrict__ C,
    const float* __restrict__ bias) {
  __shared__ __align__(16) u16 La[64 * 40];
  __shared__ __align__(16) u16 Lb[64 * 40];
  const int m0 = blockIdx.x * 64, n0 = blockIdx.y * 64;
  const int tid = threadIdx.x, l = tid & 63, w = tid >> 6;
  const int wr = w >> 1, wc = w & 1;
  const int sr = tid >> 2, sc = (tid & 3) * 8;
  float4v acc[2][2] = {};
  for (int k0 = 0; k0 < WDP; k0 += 32) {
    // A: load f32 emb directly, convert to bf16 (identical values to pre-packed path)
    int arow = m0 + sr;
    u16 pa[8];
    if (arow < VOCAB && k0 + sc + 7 < 300) {
      float4v f0 = *(const float4v*)&emb[(long long)arow * 300 + k0 + sc];
      float4v f1 = *(const float4v*)&emb[(long long)arow * 300 + k0 + sc + 4];
#pragma unroll
      for (int e = 0; e < 4; ++e) { pa[e] = f2b(f0[e]); pa[4 + e] = f2b(f1[e]); }
    } else {
#pragma unroll
      for (int e = 0; e < 8; ++e) {
        int col = k0 + sc + e;
        float v = (arow < VOCAB && col < 300) ? emb[(long long)arow * 300 + col] : 0.f;
        pa[e] = f2b(v);
      }
    }
    uint4v qa;
    qa.x = (unsigned)pa[0] | ((unsigned)pa[1] << 16);
    qa.y = (unsigned)pa[2] | ((unsigned)pa[3] << 16);
    qa.z = (unsigned)pa[4] | ((unsigned)pa[5] << 16);
    qa.w = (unsigned)pa[6] | ((unsigned)pa[7] << 16);
    uint4v qb = *(const uint4v*)&B[(long long)(n0 + sr) * WDP + k0 + sc];
    __syncthreads();
    *(uint4v*)&La[sr * 40 + sc] = qa;
    *(uint4v*)&Lb[sr * 40 + sc] = qb;
    __syncthreads();
    bf16x8 af[2], bfr[2];
#pragma unroll
    for (int mt = 0; mt < 2; ++mt)
      af[mt] = *(const bf16x8*)&La[(wr * 32 + mt * 16 + (l & 15)) * 40 + (l >> 4) * 8];
#pragma unroll
    for (int nt = 0; nt < 2; ++nt)
      bfr[nt] = *(const bf16x8*)&Lb[(wc * 32 + nt * 16 + (l & 15)) * 40 + (l >> 4) * 8];
#pragma unroll
    for (int mt = 0; mt < 2; ++mt)
#pragma unroll
      for (int nt = 0; nt < 2; ++nt)
        acc[mt][nt] = __builtin_amdgcn_mfma_f32_16x16x32_bf16(af[mt], bfr[nt], acc[mt][nt], 0, 0, 0);
  }
#pragma unroll
  for (int mt = 0; mt < 2; ++mt)
#pragma unroll
    for (int nt = 0; nt < 2; ++nt)
#pragma unroll
      for (int j = 0; j < 4; ++j) {
        int row = m0 + wr * 32 + mt * 16 + (l >> 4) * 4 + j;
        int col = n0 + wc * 32 + nt * 16 + (l & 15);
        if (row < VOCAB && col < NG)
          C[(long long)row * NG + col] = f2b(acc[mt][nt][j] + bias[col]);
      }
}

// ---------------- LSTM: 128 blocks x 4 rows x 512 threads (8 waves) ----------------
// (R13 structure, verbatim) W_hh: 40 tiles AGPR (5/wave, tiles w+8i) + 10 LDS tiles.
// Swapped-operand MFMA -> C[unit][row]; gates cross LDS once as f32 b128 (gbufF).
// E2 register-dbuf added in phase B. hid: [512 r][256 t][224 h] bf16.

__global__ __launch_bounds__(512, 2) void lstm_kernel(
    const int* __restrict__ premise, const int* __restrict__ hypothesis,
    const u16* __restrict__ E2, const u16* __restrict__ Whh,
    u16* __restrict__ hid) {
  __shared__ u16 tok[ROWS * 256];                     //   2.0 KB
  __shared__ __align__(16) u16 hbuf[16 * HS];         //   7.3 KB
  __shared__ __align__(16) float gbufF[16 * GSF];     //  50.3 KB
  __shared__ __align__(16) u16 wlds[NLDS * 16 * WLS]; //  71.3 KB -> ~131 KB total
  const int tid = threadIdx.x;
  const int l = tid & 63, w = tid >> 6;
  const int r0 = blockIdx.x * ROWS;

  for (int idx = tid; idx < ROWS * 256; idx += 512) {
    int mm = idx >> 8, tt = idx & 255;
    int row = r0 + mm;
    const int* seq = (row < 256) ? premise : hypothesis;
    tok[idx] = (u16)seq[(row & 255) * 256 + tt];
  }
  for (int idx = tid; idx < 16 * HS; idx += 512) hbuf[idx] = 0;
  // LDS-resident W_hh tiles 40..49
  for (int idx = tid; idx < NLDS * 16 * KP; idx += 512) {
    int slot = idx / (16 * KP), rem = idx % (16 * KP);
    int r = rem / KP, k = rem % KP;
    wlds[(slot * 16 + r) * WLS + k] = Whh[((40 + slot) * 16 + r) * KP + k];
  }

  // AGPR-resident W_hh: wave w owns tiles w+8i, i<NREG (0..39)
  uint4v wf[NREG][7];
#pragma unroll
  for (int i = 0; i < NREG; ++i) {
    int nt = w + 8 * i;
#pragma unroll
    for (int kf = 0; kf < 7; ++kf)
      wf[i][kf] = *(const uint4v*)&Whh[(nt * 16 + (l & 15)) * KP + kf * 32 + (l >> 4) * 8];
  }
#pragma unroll
  for (int i = 0; i < NREG; ++i)
#pragma unroll
    for (int kf = 0; kf < 7; ++kf)
      asm volatile("" : "+a"(wf[i][kf]));

  float cst[2];
  cst[0] = cst[1] = 0.f;

  // preload E2(t=0): thread owns quads u = tid + 512q (u < 800): (m=u/200, j=u%200)
  ushort4v ev[2];
#pragma unroll
  for (int q = 0; q < 2; ++q) {
    int u = tid + 512 * q;
    if (u < ROWS * 200) {
      int m = u / 200, j = u - m * 200;
      int tk = tok[m * 256];
      ev[q] = *(const ushort4v*)&E2[(long long)tk * NG + 4 * j];
    }
  }
  __syncthreads();

  for (int t = 0; t < SS; ++t) {
    // coalesced hid write of h(t-1)
    if (t > 0) {
      const unsigned* hb32 = (const unsigned*)hbuf;
      unsigned* hid32 = (unsigned*)hid;
      if (tid < ROWS * 112) {
        int m2 = tid / 112, c = tid - 112 * m2;
        hid32[((long long)(r0 + m2) * SS + (t - 1)) * 112 + c] = hb32[m2 * 116 + c];
      }
    }

    // prefetch E2 for t+1
    int t2 = (t < SS - 1) ? t + 1 : t;
    ushort4v evn[2];
#pragma unroll
    for (int q = 0; q < 2; ++q) {
      int u = tid + 512 * q;
      if (u < ROWS * 200) {
        int m = u / 200, j = u - m * 200;
        int tk = tok[m * 256 + t2];
        evn[q] = *(const ushort4v*)&E2[(long long)tk * NG + 4 * j];
      }
    }

    // A-fragments (h(t-1)) from hbuf
    bf16x8 af[7];
#pragma unroll
    for (int kf = 0; kf < 7; ++kf)
      af[kf] = *(const bf16x8*)&hbuf[(l & 15) * HS + kf * 32 + (l >> 4) * 8];

    // ---- phase A: W@h -> gbufF (C[unit'][row]; write b128 per tile) ----
    {
      float4v acc[NREG];
#pragma unroll
      for (int i = 0; i < NREG; ++i) acc[i] = float4v{0.f, 0.f, 0.f, 0.f};
      asm volatile("s_nop 1"
                   : "+v"(acc[0]), "+v"(acc[1]), "+v"(acc[2]), "+v"(acc[3]), "+v"(acc[4]));
#pragma unroll
      for (int kf = 0; kf < 7; ++kf)
#pragma unroll
        for (int i = 0; i < NREG; ++i)
          asm volatile("v_mfma_f32_16x16x32_bf16 %0, %1, %2, %0"
                       : "+v"(acc[i])
                       : "a"(wf[i][kf]), "v"(af[kf]));
      asm volatile("s_nop 7\n\ts_nop 7"
                   : "+v"(acc[0]), "+v"(acc[1]), "+v"(acc[2]), "+v"(acc[3]), "+v"(acc[4]));
#pragma unroll
      for (int i = 0; i < NREG; ++i) {
        int nt = w + 8 * i;
        *(float4v*)&gbufF[(l & 15) * GSF + nt * 16 + (l >> 4) * 4] = acc[i];
      }
    }
    // LDS tiles: slot w (tile 40+w); waves 0,1 also slot 8+w (tiles 48,49)
    {
      float4v a2 = {0.f, 0.f, 0.f, 0.f};
#pragma unroll
      for (int kf = 0; kf < 7; ++kf) {
        bf16x8 bfr = *(const bf16x8*)&wlds[(w * 16 + (l & 15)) * WLS + kf * 32 + (l >> 4) * 8];
        a2 = __builtin_amdgcn_mfma_f32_16x16x32_bf16(bfr, af[kf], a2, 0, 0, 0);
      }
      *(float4v*)&gbufF[(l & 15) * GSF + (40 + w) * 16 + (l >> 4) * 4] = a2;
    }
    if (w < 2) {
      int slot = 8 + w;
      float4v a2 = {0.f, 0.f, 0.f, 0.f};
#pragma unroll
      for (int kf = 0; kf < 7; ++kf) {
        bf16x8 bfr = *(const bf16x8*)&wlds[(slot * 16 + (l & 15)) * WLS + kf * 32 + (l >> 4) * 8];
        a2 = __builtin_amdgcn_mfma_f32_16x16x32_bf16(bfr, af[kf], a2, 0, 0, 0);
      }
      *(float4v*)&gbufF[(l & 15) * GSF + (48 + w) * 16 + (l >> 4) * 4] = a2;
    }
    __syncthreads();

    // ---- phase B: gates = gbufF + E2(reg) -> nonlinearity -> h(t) ----
#pragma unroll
    for (int q = 0; q < 2; ++q) {
      int u = tid + 512 * q;
      if (u < ROWS * 200) {
        int m = u / 200, j = u - m * 200;
        float4v gv = *(const float4v*)&gbufF[m * GSF + 4 * j];
        float gi = gv[0] + b2f(ev[q].x);
        float gf = gv[1] + b2f(ev[q].y);
        float gg = gv[2] + b2f(ev[q].z);
        float go = gv[3] + b2f(ev[q].w);
        float cn = sigm(gf) * cst[q] + sigm(gi) * tanh_f(gg);
        float hn = sigm(go) * tanh_f(cn);
        cst[q] = cn;
        hbuf[m * HS + j] = f2b(hn);
      }
    }
    ev[0] = evn[0]; ev[1] = evn[1];
    __syncthreads();
  }

  // epilogue: write h(255)
  {
    const unsigned* hb32 = (const unsigned*)hbuf;
    unsigned* hid32 = (unsigned*)hid;
    if (tid < ROWS * 112) {
      int m2 = tid / 112, c = tid - 112 * m2;
      hid32[((long long)(r0 + m2) * SS + (SS - 1)) * 112 + c] = hb32[m2 * 116 + c];
    }
  }
}

// ---------------- attn (NT): X[b][i][j] = sum_h Hp[i][h]*Hh[j][h], bf16 out --------

__global__ __launch_bounds__(256, 2) void gemm_attn(const u16* __restrict__ H,
                                                    u16* __restrict__ X) {
  __shared__ __align__(16) u16 La[64 * 40];
  __shared__ __align__(16) u16 Lb[64 * 40];
  const int z = blockIdx.z;
  const u16* A = H + (long long)z * SS * KP;
  const u16* B = H + (long long)(z + 256) * SS * KP;
  u16* C = X + (long long)z * 65536;
  const int m0 = blockIdx.x * 64, n0 = blockIdx.y * 64;
  const int tid = threadIdx.x, l = tid & 63, w = tid >> 6;
  const int wr = w >> 1, wc = w & 1;
  const int sr = tid >> 2, sc = (tid & 3) * 8;
  float4v acc[2][2] = {};
  for (int k0 = 0; k0 < KP; k0 += 32) {
    uint4v qa = *(const uint4v*)&A[(m0 + sr) * KP + k0 + sc];
    uint4v qb = *(const uint4v*)&B[(n0 + sr) * KP + k0 + sc];
    __syncthreads();
    *(uint4v*)&La[sr * 40 + sc] = qa;
    *(uint4v*)&Lb[sr * 40 + sc] = qb;
    __syncthreads();
    bf16x8 af[2], bfr[2];
#pragma unroll
    for (int mt = 0; mt < 2; ++mt)
      af[mt] = *(const bf16x8*)&La[(wr * 32 + mt * 16 + (l & 15)) * 40 + (l >> 4) * 8];
#pragma unroll
    for (int nt = 0; nt < 2; ++nt)
      bfr[nt] = *(const bf16x8*)&Lb[(wc * 32 + nt * 16 + (l & 15)) * 40 + (l >> 4) * 8];
#pragma unroll
    for (int mt = 0; mt < 2; ++mt)
#pragma unroll
      for (int nt = 0; nt < 2; ++nt)
        acc[mt][nt] = __builtin_amdgcn_mfma_f32_16x16x32_bf16(af[mt], bfr[nt], acc[mt][nt], 0, 0, 0);
  }
#pragma unroll
  for (int mt = 0; mt < 2; ++mt)
#pragma unroll
    for (int nt = 0; nt < 2; ++nt)
#pragma unroll
      for (int j = 0; j < 4; ++j) {
        int row = m0 + wr * 32 + mt * 16 + (l >> 4) * 4 + j;
        int col = n0 + wc * 32 + nt * 16 + (l & 15);
        C[row * SS + col] = f2b(acc[mt][nt][j]);
      }
}

// ---------------- softmax stats ----------------

__global__ void rowstats(const u16* __restrict__ X, float* __restrict__ rm,
                         float* __restrict__ ri) {
  int r = blockIdx.x * 4 + (threadIdx.x >> 6);
  int l = threadIdx.x & 63;
  ushort4v q = *(const ushort4v*)(X + (long long)r * 256 + l * 4);
  float v0 = b2f(q.x), v1 = b2f(q.y), v2 = b2f(q.z), v3 = b2f(q.w);
  float m = fmaxf(fmaxf(v0, v1), fmaxf(v2, v3));
#pragma unroll
  for (int off = 32; off; off >>= 1) m = fmaxf(m, __shfl_xor(m, off));
  float s = __expf(v0 - m) + __expf(v1 - m) + __expf(v2 - m) + __expf(v3 - m);
#pragma unroll
  for (int off = 32; off; off >>= 1) s += __shfl_xor(s, off);
  if (l == 0) { rm[r] = m; ri[r] = 1.f / s; }
}

__global__ void colstats(const u16* __restrict__ X, float* __restrict__ cm,
                         float* __restrict__ ci) {
  int b = blockIdx.x, j0 = blockIdx.y * 16;
  int tid = threadIdx.x, jj = tid & 15, iq = tid >> 4;
  const u16* base = X + (long long)b * 65536;
  float v[16];
  float m = -1e30f;
#pragma unroll
  for (int ch = 0; ch < 16; ++ch) {
    v[ch] = b2f(base[(ch * 16 + iq) * 256 + j0 + jj]);
    m = fmaxf(m, v[ch]);
  }
  __shared__ float red[256];
  red[tid] = m; __syncthreads();
#pragma unroll
  for (int off = 128; off >= 16; off >>= 1) {
    if (tid < off) red[tid] = fmaxf(red[tid], red[tid + off]);
    __syncthreads();
  }
  float mm = red[jj]; __syncthreads();
  float s = 0.f;
#pragma unroll
  for (int ch = 0; ch < 16; ++ch) s += __expf(v[ch] - mm);
  red[tid] = s; __syncthreads();
#pragma unroll
  for (int off = 128; off >= 16; off >>= 1) {
    if (tid < off) red[tid] += red[tid + off];
    __syncthreads();
  }
  if (tid < 16) { cm[b * 256 + j0 + tid] = mm; ci[b * 256 + j0 + tid] = 1.f / red[tid]; }
}

// ---------------- PV GEMMs: on-the-fly softmax A, transpose-staged V from hid ------
// TRANSA=0: C[i][h] = sum_j exp(X[i][j]-rm[i])*ri[i] * Hh[j][h]
// TRANSA=1: C[j][h] = sum_i exp(X[i][j]-cm[j])*ci[j] * Hp[i][h]
// pmax[(z*4+blockIdx.x)*256 + col] = max over the tile's 64 rows

template <int TRANSA>
__global__ __launch_bounds__(256, 2) void gemm_pv(
    const u16* __restrict__ X, const u16* __restrict__ H,
    const float* __restrict__ sm, const float* __restrict__ sinv,
    float* __restrict__ pmax) {
  __shared__ __align__(16) u16 La[64 * 40];
  __shared__ __align__(16) u16 Lb[64 * 40];
  __shared__ float red[8][64];
  const int z = blockIdx.z;
  const u16* Xz = X + (long long)z * 65536;
  const u16* B = H + (long long)(TRANSA ? z : z + 256) * SS * KP;
  const int m0 = blockIdx.x * 64, n0 = blockIdx.y * 64;
  const int tid = threadIdx.x, l = tid & 63, w = tid >> 6;
  const int wr = w >> 1, wc = w & 1;
  const int sr = tid >> 2, sc = (tid & 3) * 8;
  const int sr2 = tid >> 3, sc2 = (tid & 7) * 8;

  float m_s0 = 0.f, i_s0 = 0.f;
  float mj[8], ij[8];
  if (TRANSA == 0) {
    m_s0 = sm[z * 256 + m0 + sr];
    i_s0 = sinv[z * 256 + m0 + sr];
  } else {
#pragma unroll
    for (int e = 0; e < 8; ++e) {
      mj[e] = sm[z * 256 + m0 + sc2 + e];
      ij[e] = sinv[z * 256 + m0 + sc2 + e];
    }
  }

  float4v acc[2][2] = {};
  for (int k0 = 0; k0 < SS; k0 += 32) {
    union { uint4v v; u16 s[8]; } ua, ub;
    if (TRANSA == 0)
      ua.v = *(const uint4v*)&Xz[(m0 + sr) * SS + k0 + sc];
    else
      ua.v = *(const uint4v*)&Xz[(k0 + sr2) * SS + m0 + sc2];
    ub.v = *(const uint4v*)&B[(long long)(k0 + sr2) * KP + n0 + sc2];
    __syncthreads();
    if (TRANSA == 0) {
      u16 pa[8];
#pragma unroll
      for (int e = 0; e < 8; ++e)
        pa[e] = f2b(__expf(b2f(ua.s[e]) - m_s0) * i_s0);
      uint4v pk;
      pk.x = (unsigned)pa[0] | ((unsigned)pa[1] << 16);
      pk.y = (unsigned)pa[2] | ((unsigned)pa[3] << 16);
      pk.z = (unsigned)pa[4] | ((unsigned)pa[5] << 16);
      pk.w = (unsigned)pa[6] | ((unsigned)pa[7] << 16);
      *(uint4v*)&La[sr * 40 + sc] = pk;
    } else {
#pragma unroll
      for (int e = 0; e < 8; ++e)
        La[(sc2 + e) * 40 + sr2] = f2b(__expf(b2f(ua.s[e]) - mj[e]) * ij[e]);
    }
    // V staged transposed: Lb[hcol][k] from hid rows (k) x hcols
#pragma unroll
    for (int e = 0; e < 8; ++e)
      Lb[(sc2 + e) * 40 + sr2] = (n0 + sc2 + e < KP) ? ub.s[e] : (u16)0;
    __syncthreads();
    bf16x8 af[2], bfr[2];
#pragma unroll
    for (int mt = 0; mt < 2; ++mt)
      af[mt] = *(const bf16x8*)&La[(wr * 32 + mt * 16 + (l & 15)) * 40 + (l >> 4) * 8];
#pragma unroll
    for (int nt = 0; nt < 2; ++nt)
      bfr[nt] = *(const bf16x8*)&Lb[(wc * 32 + nt * 16 + (l & 15)) * 40 + (l >> 4) * 8];
#pragma unroll
    for (int mt = 0; mt < 2; ++mt)
#pragma unroll
      for (int nt = 0; nt < 2; ++nt)
        acc[mt][nt] = __builtin_amdgcn_mfma_f32_16x16x32_bf16(af[mt], bfr[nt], acc[mt][nt], 0, 0, 0);
  }
  // fused max over the 64 tile rows
#pragma unroll
  for (int nt = 0; nt < 2; ++nt) {
    float v = -1e30f;
#pragma unroll
    for (int mt = 0; mt < 2; ++mt)
#pragma unroll
      for (int j = 0; j < 4; ++j) v = fmaxf(v, acc[mt][nt][j]);
    red[wr * 4 + (l >> 4)][wc * 32 + nt * 16 + (l & 15)] = v;
  }
  __syncthreads();
  if (tid < 64) {
    float m = red[0][tid];
#pragma unroll
    for (int g = 1; g < 8; ++g) m = fmaxf(m, red[g][tid]);
    pmax[((long long)z * 4 + blockIdx.x) * 256 + n0 + tid] = m;
  }
}

__global__ void maxfinal(const float* __restrict__ p1, const float* __restrict__ p2,
                         float* __restrict__ hq, float* __restrict__ hs) {
  int b = blockIdx.x, h = threadIdx.x;
  if (h < HID) {
    float m1 = -1e30f, m2 = -1e30f;
#pragma unroll
    for (int x = 0; x < 4; ++x) {
      m1 = fmaxf(m1, p1[(b * 4 + x) * 256 + h]);
      m2 = fmaxf(m2, p2[(b * 4 + x) * 256 + h]);
    }
    hq[b * HID + h] = m1;
    hs[b * HID + h] = m2;
  }
}

// ---------------- head: feat -> logits -> log_softmax (f32 out) ----------------

__global__ void final_k(const float* __restrict__ hq, const float* __restrict__ hs,
                        const float* __restrict__ Wl, const float* __restrict__ bl,
                        float* __restrict__ out) {
  int b = blockIdx.x, t = threadIdx.x;
  float a0 = 0.f, a1v = 0.f, a2v = 0.f;
  for (int hp = t; hp < 800; hp += 256) {
    int part = hp / 200, u = hp - part * 200;
    float q = hq[b * HID + u], s = hs[b * HID + u];
    float f = (part == 0) ? q : (part == 1) ? s : (part == 2) ? (q - s) : (q * s);
    a0 += f * Wl[hp]; a1v += f * Wl[800 + hp]; a2v += f * Wl[1600 + hp];
  }
#pragma unroll
  for (int off = 32; off; off >>= 1) {
    a0 += __shfl_xor(a0, off); a1v += __shfl_xor(a1v, off); a2v += __shfl_xor(a2v, off);
  }
  __shared__ float rr[12];
  int w = t >> 6;
  if ((t & 63) == 0) { rr[w] = a0; rr[4 + w] = a1v; rr[8 + w] = a2v; }
  __syncthreads();
  if (t == 0) {
    float l0 = rr[0] + rr[1] + rr[2] + rr[3] + bl[0];
    float l1 = rr[4] + rr[5] + rr[6] + rr[7] + bl[1];
    float l2 = rr[8] + rr[9] + rr[10] + rr[11] + bl[2];
    float mm = fmaxf(l0, fmaxf(l1, l2));
    float lse = mm + __logf(__expf(l0 - mm) + __expf(l1 - mm) + __expf(l2 - mm));
    out[b * 3 + 0] = l0 - lse;
    out[b * 3 + 1] = l1 - lse;
    out[b * 3 + 2] = l2 - lse;
  }
}

// ---------------- host ----------------

extern "C" void kernel_launch(void* const* d_in, const int* in_sizes, int n_in,
                              void* d_out, int out_size, void* d_ws, size_t ws_size,
                              hipStream_t stream) {
  const int* premise = (const int*)d_in[0];
  const int* hypothesis = (const int*)d_in[1];
  const float* emb = (const float*)d_in[2];
  const float* W_ih = (const float*)d_in[3];
  const float* W_hh = (const float*)d_in[4];
  const float* b_ih = (const float*)d_in[5];
  const float* b_hh = (const float*)d_in[6];
  const float* W_last = (const float*)d_in[7];
  const float* b_last = (const float*)d_in[8];
  float* out = (float*)d_out;

  char* ws = (char*)d_ws;
  // layout (bytes), peak = 118,664,064 (~113 MB)
  const size_t O_hid  = 0;          // [512][256][224] bf16 = 58,720,256
  const size_t O_E2   = 58720256;   // [36906][800] bf16 = 59,049,600 (dead after LSTM)
  const size_t O_X    = 58720256;   // [256][256][256] bf16 = 33,554,432 (overlays dead E2)
  const size_t O_rm   = 92274688;   // 65536 f32 (overlays dead E2 tail)
  const size_t O_ri   = 92536832;
  const size_t O_cm   = 92798976;
  const size_t O_ci   = 93061120;
  const size_t O_p1   = 93323264;   // [256][4][256] f32
  const size_t O_p2   = 94371840;
  const size_t O_hq   = 95420416;   // [256][200] f32
  const size_t O_hs   = 95625216;
  const size_t O_whh  = 117769856;  // [800][224] bf16 (live through LSTM, after E2 end)
  const size_t O_wih  = 118128256;  // [832][320] bf16
  const size_t O_bias = 118660736;  // 832 f32 -> end 118,664,064

  u16* hid  = (u16*)(ws + O_hid);
  u16* E2   = (u16*)(ws + O_E2);
  u16* X    = (u16*)(ws + O_X);
  float* rm = (float*)(ws + O_rm);
  float* ri = (float*)(ws + O_ri);
  float* cm = (float*)(ws + O_cm);
  float* ci = (float*)(ws + O_ci);
  float* p1 = (float*)(ws + O_p1);
  float* p2 = (float*)(ws + O_p2);
  float* hq = (float*)(ws + O_hq);
  float* hs = (float*)(ws + O_hs);
  u16* whhB = (u16*)(ws + O_whh);
  u16* wihB = (u16*)(ws + O_wih);
  float* biasP = (float*)(ws + O_bias);

  conv_pack<<<(R0N + R1N + R2N + 255) / 256, 256, 0, stream>>>(
      W_ih, W_hh, b_ih, b_hh, wihB, whhB, biasP);

  gemm_e2<<<dim3(VPAD / 64, NGP / 64), 256, 0, stream>>>(emb, wihB, E2, biasP);

  lstm_kernel<<<128, 512, 0, stream>>>(premise, hypothesis, E2, whhB, hid);

  gemm_attn<<<dim3(4, 4, 256), 256, 0, stream>>>(hid, X);

  rowstats<<<16384, 256, 0, stream>>>(X, rm, ri);
  colstats<<<dim3(256, 16), 256, 0, stream>>>(X, cm, ci);

  gemm_pv<0><<<dim3(4, 4, 256), 256, 0, stream>>>(X, hid, rm, ri, p1);
  gemm_pv<1><<<dim3(4, 4, 256), 256, 0, stream>>>(X, hid, cm, ci, p2);

  maxfinal<<<256, 256, 0, stream>>>(p1, p2, hq, hs);
  final_k<<<256, 256, 0, stream>>>(hq, hs, W_last, b_last, out);
}

// Round 16
// 748.174 us; speedup vs baseline: 1.4778x; 1.0608x over previous
//
#include <hip/hip_runtime.h>

typedef unsigned short u16;
typedef __attribute__((ext_vector_type(8))) __bf16 bf16x8;
typedef __attribute__((ext_vector_type(4))) float float4v;
typedef __attribute__((ext_vector_type(4))) u16 ushort4v;
typedef __attribute__((ext_vector_type(4))) unsigned int uint4v;

#define VOCAB 36906
#define VPAD  36928   // 577*64
#define WDP   320     // K-pad of 300 for emb GEMM
#define HID   200
#define NG    800     // 4H
#define NGP   832     // 13*64
#define KP    224     // 7*32 (H padded)
#define SS    256
#define ROWS  4       // LSTM rows per block (128 blocks)
#define HS    232     // hbuf row stride (u16)
#define GSF   804     // gbufF row stride (f32)
#define WLS   228     // wlds row stride (u16)
#define NREG  5       // AGPR-resident W_hh tiles per wave (tiles w+8i -> 0..39)
#define NLDS  10      // LDS-resident tiles 40..49

__device__ __forceinline__ float b2f(u16 u) {
  union { unsigned int i; float f; } c; c.i = ((unsigned int)u) << 16; return c.f;
}
__device__ __forceinline__ u16 f2b(float f) {
  union { float f; unsigned int i; } c; c.f = f;
  unsigned int u = c.i;
  u += 0x7fffu + ((u >> 16) & 1u);
  return (u16)(u >> 16);
}
__device__ __forceinline__ float sigm(float x) { return 1.f / (1.f + __expf(-x)); }
__device__ __forceinline__ float tanh_f(float x) {
  float e = __expf(2.f * x);
  return 1.f - 2.f / (e + 1.f);
}

// ---------------- packing ----------------

__global__ void conv_emb(const float* __restrict__ emb, u16* __restrict__ out) {
  for (long long idx = (long long)blockIdx.x * 256 + threadIdx.x;
       idx < (long long)VPAD * WDP; idx += (long long)gridDim.x * 256) {
    int v = (int)(idx / WDP), k = (int)(idx % WDP);
    float val = (v < VOCAB && k < 300) ? emb[(long long)v * 300 + k] : 0.f;
    out[idx] = f2b(val);
  }
}

// W_ih (permuted n'=4j+gate, K-pad 320) + W_hh (permuted, K-pad 224) + bias, fused
#define R0N (NGP * WDP)
#define R1N (NG * KP)
#define R2N (NGP)

__global__ void conv_pack(const float* __restrict__ Wih, const float* __restrict__ Whh,
                          const float* __restrict__ bi, const float* __restrict__ bh,
                          u16* __restrict__ wihB, u16* __restrict__ whhB,
                          float* __restrict__ biasP) {
  int idx = blockIdx.x * 256 + threadIdx.x;
  if (idx < R0N) {
    int n = idx / WDP, k = idx % WDP;
    float v = 0.f;
    if (n < NG && k < 300) { int gt = n & 3, j = n >> 2; v = Wih[(gt * HID + j) * 300 + k]; }
    wihB[idx] = f2b(v);
  } else if (idx < R0N + R1N) {
    int r = idx - R0N;
    int n = r / KP, k = r % KP;
    int gt = n & 3, j = n >> 2;
    float v = (k < HID) ? Whh[(gt * HID + j) * HID + k] : 0.f;
    whhB[r] = f2b(v);
  } else if (idx < R0N + R1N + R2N) {
    int n = idx - R0N - R1N;
    float v = 0.f;
    if (n < NG) { int gt = n & 3, j = n >> 2; v = bi[gt * HID + j] + bh[gt * HID + j]; }
    biasP[n] = v;
  }
}

// ---------------- E2 = emb @ W_ih'^T + bias  (NT GEMM, bf16 A) ----------------

__global__ __launch_bounds__(256, 2) void gemm_e2(
    const u16* __restrict__ A, const u16* __restrict__ B, u16* __restrict__ C,
    const float* __restrict__ bias) {
  __shared__ __align__(16) u16 La[64 * 40];
  __shared__ __align__(16) u16 Lb[64 * 40];
  const int m0 = blockIdx.x * 64, n0 = blockIdx.y * 64;
  const int tid = threadIdx.x, l = tid & 63, w = tid >> 6;
  const int wr = w >> 1, wc = w & 1;
  const int sr = tid >> 2, sc = (tid & 3) * 8;
  float4v acc[2][2] = {};
  for (int k0 = 0; k0 < WDP; k0 += 32) {
    uint4v qa = *(const uint4v*)&A[(long long)(m0 + sr) * WDP + k0 + sc];
    uint4v qb = *(const uint4v*)&B[(long long)(n0 + sr) * WDP + k0 + sc];
    __syncthreads();
    *(uint4v*)&La[sr * 40 + sc] = qa;
    *(uint4v*)&Lb[sr * 40 + sc] = qb;
    __syncthreads();
    bf16x8 af[2], bfr[2];
#pragma unroll
    for (int mt = 0; mt < 2; ++mt)
      af[mt] = *(const bf16x8*)&La[(wr * 32 + mt * 16 + (l & 15)) * 40 + (l >> 4) * 8];
#pragma unroll
    for (int nt = 0; nt < 2; ++nt)
      bfr[nt] = *(const bf16x8*)&Lb[(wc * 32 + nt * 16 + (l & 15)) * 40 + (l >> 4) * 8];
#pragma unroll
    for (int mt = 0; mt < 2; ++mt)
#pragma unroll
      for (int nt = 0; nt < 2; ++nt)
        acc[mt][nt] = __builtin_amdgcn_mfma_f32_16x16x32_bf16(af[mt], bfr[nt], acc[mt][nt], 0, 0, 0);
  }
#pragma unroll
  for (int mt = 0; mt < 2; ++mt)
#pragma unroll
    for (int nt = 0; nt < 2; ++nt)
#pragma unroll
      for (int j = 0; j < 4; ++j) {
        int row = m0 + wr * 32 + mt * 16 + (l >> 4) * 4 + j;
        int col = n0 + wc * 32 + nt * 16 + (l & 15);
        if (row < VOCAB && col < NG)
          C[(long long)row * NG + col] = f2b(acc[mt][nt][j] + bias[col]);
      }
}

// ---------------- LSTM: 128 blocks x 4 rows x 512 threads (8 waves) ----------------
// (R13 structure) W_hh: 40 tiles AGPR (5/wave, tiles w+8i) + 10 LDS tiles.
// Swapped-operand MFMA -> C[unit][row]; gates cross LDS once as f32 b128 (gbufF).
// E2 register-dbuf added in phase B. hid: [512 r][256 t][224 h] bf16.

__global__ __launch_bounds__(512, 2) void lstm_kernel(
    const int* __restrict__ premise, const int* __restrict__ hypothesis,
    const u16* __restrict__ E2, const u16* __restrict__ Whh,
    u16* __restrict__ hid) {
  __shared__ u16 tok[ROWS * 256];                     //   2.0 KB
  __shared__ __align__(16) u16 hbuf[16 * HS];         //   7.3 KB
  __shared__ __align__(16) float gbufF[16 * GSF];     //  50.3 KB
  __shared__ __align__(16) u16 wlds[NLDS * 16 * WLS]; //  71.3 KB -> ~131 KB total
  const int tid = threadIdx.x;
  const int l = tid & 63, w = tid >> 6;
  const int r0 = blockIdx.x * ROWS;

  for (int idx = tid; idx < ROWS * 256; idx += 512) {
    int mm = idx >> 8, tt = idx & 255;
    int row = r0 + mm;
    const int* seq = (row < 256) ? premise : hypothesis;
    tok[idx] = (u16)seq[(row & 255) * 256 + tt];
  }
  for (int idx = tid; idx < 16 * HS; idx += 512) hbuf[idx] = 0;
  // LDS-resident W_hh tiles 40..49
  for (int idx = tid; idx < NLDS * 16 * KP; idx += 512) {
    int slot = idx / (16 * KP), rem = idx % (16 * KP);
    int r = rem / KP, k = rem % KP;
    wlds[(slot * 16 + r) * WLS + k] = Whh[((40 + slot) * 16 + r) * KP + k];
  }

  // AGPR-resident W_hh: wave w owns tiles w+8i, i<NREG (0..39)
  uint4v wf[NREG][7];
#pragma unroll
  for (int i = 0; i < NREG; ++i) {
    int nt = w + 8 * i;
#pragma unroll
    for (int kf = 0; kf < 7; ++kf)
      wf[i][kf] = *(const uint4v*)&Whh[(nt * 16 + (l & 15)) * KP + kf * 32 + (l >> 4) * 8];
  }
#pragma unroll
  for (int i = 0; i < NREG; ++i)
#pragma unroll
    for (int kf = 0; kf < 7; ++kf)
      asm volatile("" : "+a"(wf[i][kf]));

  float cst[2];
  cst[0] = cst[1] = 0.f;

  // preload E2(t=0): thread owns quads u = tid + 512q (u < 800): (m=u/200, j=u%200)
  ushort4v ev[2];
#pragma unroll
  for (int q = 0; q < 2; ++q) {
    int u = tid + 512 * q;
    if (u < ROWS * 200) {
      int m = u / 200, j = u - m * 200;
      int tk = tok[m * 256];
      ev[q] = *(const ushort4v*)&E2[(long long)tk * NG + 4 * j];
    }
  }
  __syncthreads();

  for (int t = 0; t < SS; ++t) {
    // coalesced hid write of h(t-1)
    if (t > 0) {
      const unsigned* hb32 = (const unsigned*)hbuf;
      unsigned* hid32 = (unsigned*)hid;
      if (tid < ROWS * 112) {
        int m2 = tid / 112, c = tid - 112 * m2;
        hid32[((long long)(r0 + m2) * SS + (t - 1)) * 112 + c] = hb32[m2 * 116 + c];
      }
    }

    // prefetch E2 for t+1
    int t2 = (t < SS - 1) ? t + 1 : t;
    ushort4v evn[2];
#pragma unroll
    for (int q = 0; q < 2; ++q) {
      int u = tid + 512 * q;
      if (u < ROWS * 200) {
        int m = u / 200, j = u - m * 200;
        int tk = tok[m * 256 + t2];
        evn[q] = *(const ushort4v*)&E2[(long long)tk * NG + 4 * j];
      }
    }

    // A-fragments (h(t-1)) from hbuf
    bf16x8 af[7];
#pragma unroll
    for (int kf = 0; kf < 7; ++kf)
      af[kf] = *(const bf16x8*)&hbuf[(l & 15) * HS + kf * 32 + (l >> 4) * 8];

    // ---- phase A: W@h -> gbufF (C[unit'][row]; write b128 per tile) ----
    {
      float4v acc[NREG];
#pragma unroll
      for (int i = 0; i < NREG; ++i) acc[i] = float4v{0.f, 0.f, 0.f, 0.f};
      asm volatile("s_nop 1"
                   : "+v"(acc[0]), "+v"(acc[1]), "+v"(acc[2]), "+v"(acc[3]), "+v"(acc[4]));
#pragma unroll
      for (int kf = 0; kf < 7; ++kf)
#pragma unroll
        for (int i = 0; i < NREG; ++i)
          asm volatile("v_mfma_f32_16x16x32_bf16 %0, %1, %2, %0"
                       : "+v"(acc[i])
                       : "a"(wf[i][kf]), "v"(af[kf]));
      asm volatile("s_nop 7\n\ts_nop 7"
                   : "+v"(acc[0]), "+v"(acc[1]), "+v"(acc[2]), "+v"(acc[3]), "+v"(acc[4]));
#pragma unroll
      for (int i = 0; i < NREG; ++i) {
        int nt = w + 8 * i;
        *(float4v*)&gbufF[(l & 15) * GSF + nt * 16 + (l >> 4) * 4] = acc[i];
      }
    }
    // LDS tiles: slot w (tile 40+w); waves 0,1 also slot 8+w (tiles 48,49)
    {
      float4v a2 = {0.f, 0.f, 0.f, 0.f};
#pragma unroll
      for (int kf = 0; kf < 7; ++kf) {
        bf16x8 bfr = *(const bf16x8*)&wlds[(w * 16 + (l & 15)) * WLS + kf * 32 + (l >> 4) * 8];
        a2 = __builtin_amdgcn_mfma_f32_16x16x32_bf16(bfr, af[kf], a2, 0, 0, 0);
      }
      *(float4v*)&gbufF[(l & 15) * GSF + (40 + w) * 16 + (l >> 4) * 4] = a2;
    }
    if (w < 2) {
      int slot = 8 + w;
      float4v a2 = {0.f, 0.f, 0.f, 0.f};
#pragma unroll
      for (int kf = 0; kf < 7; ++kf) {
        bf16x8 bfr = *(const bf16x8*)&wlds[(slot * 16 + (l & 15)) * WLS + kf * 32 + (l >> 4) * 8];
        a2 = __builtin_amdgcn_mfma_f32_16x16x32_bf16(bfr, af[kf], a2, 0, 0, 0);
      }
      *(float4v*)&gbufF[(l & 15) * GSF + (48 + w) * 16 + (l >> 4) * 4] = a2;
    }
    __syncthreads();

    // ---- phase B: gates = gbufF + E2(reg) -> nonlinearity -> h(t) ----
#pragma unroll
    for (int q = 0; q < 2; ++q) {
      int u = tid + 512 * q;
      if (u < ROWS * 200) {
        int m = u / 200, j = u - m * 200;
        float4v gv = *(const float4v*)&gbufF[m * GSF + 4 * j];
        float gi = gv[0] + b2f(ev[q].x);
        float gf = gv[1] + b2f(ev[q].y);
        float gg = gv[2] + b2f(ev[q].z);
        float go = gv[3] + b2f(ev[q].w);
        float cn = sigm(gf) * cst[q] + sigm(gi) * tanh_f(gg);
        float hn = sigm(go) * tanh_f(cn);
        cst[q] = cn;
        hbuf[m * HS + j] = f2b(hn);
      }
    }
    ev[0] = evn[0]; ev[1] = evn[1];
    __syncthreads();
  }

  // epilogue: write h(255)
  {
    const unsigned* hb32 = (const unsigned*)hbuf;
    unsigned* hid32 = (unsigned*)hid;
    if (tid < ROWS * 112) {
      int m2 = tid / 112, c = tid - 112 * m2;
      hid32[((long long)(r0 + m2) * SS + (SS - 1)) * 112 + c] = hb32[m2 * 116 + c];
    }
  }
}

// ---------------- attn (NT): X[b][i][j] = sum_h Hp[i][h]*Hh[j][h], bf16 out --------

__global__ __launch_bounds__(256, 2) void gemm_attn(const u16* __restrict__ H,
                                                    u16* __restrict__ X) {
  __shared__ __align__(16) u16 La[64 * 40];
  __shared__ __align__(16) u16 Lb[64 * 40];
  const int z = blockIdx.z;
  const u16* A = H + (long long)z * SS * KP;
  const u16* B = H + (long long)(z + 256) * SS * KP;
  u16* C = X + (long long)z * 65536;
  const int m0 = blockIdx.x * 64, n0 = blockIdx.y * 64;
  const int tid = threadIdx.x, l = tid & 63, w = tid >> 6;
  const int wr = w >> 1, wc = w & 1;
  const int sr = tid >> 2, sc = (tid & 3) * 8;
  float4v acc[2][2] = {};
  for (int k0 = 0; k0 < KP; k0 += 32) {
    uint4v qa = *(const uint4v*)&A[(m0 + sr) * KP + k0 + sc];
    uint4v qb = *(const uint4v*)&B[(n0 + sr) * KP + k0 + sc];
    __syncthreads();
    *(uint4v*)&La[sr * 40 + sc] = qa;
    *(uint4v*)&Lb[sr * 40 + sc] = qb;
    __syncthreads();
    bf16x8 af[2], bfr[2];
#pragma unroll
    for (int mt = 0; mt < 2; ++mt)
      af[mt] = *(const bf16x8*)&La[(wr * 32 + mt * 16 + (l & 15)) * 40 + (l >> 4) * 8];
#pragma unroll
    for (int nt = 0; nt < 2; ++nt)
      bfr[nt] = *(const bf16x8*)&Lb[(wc * 32 + nt * 16 + (l & 15)) * 40 + (l >> 4) * 8];
#pragma unroll
    for (int mt = 0; mt < 2; ++mt)
#pragma unroll
      for (int nt = 0; nt < 2; ++nt)
        acc[mt][nt] = __builtin_amdgcn_mfma_f32_16x16x32_bf16(af[mt], bfr[nt], acc[mt][nt], 0, 0, 0);
  }
#pragma unroll
  for (int mt = 0; mt < 2; ++mt)
#pragma unroll
    for (int nt = 0; nt < 2; ++nt)
#pragma unroll
      for (int j = 0; j < 4; ++j) {
        int row = m0 + wr * 32 + mt * 16 + (l >> 4) * 4 + j;
        int col = n0 + wc * 32 + nt * 16 + (l & 15);
        C[row * SS + col] = f2b(acc[mt][nt][j]);
      }
}

// ---------------- softmax stats ----------------

__global__ void rowstats(const u16* __restrict__ X, float* __restrict__ rm,
                         float* __restrict__ ri) {
  int r = blockIdx.x * 4 + (threadIdx.x >> 6);
  int l = threadIdx.x & 63;
  ushort4v q = *(const ushort4v*)(X + (long long)r * 256 + l * 4);
  float v0 = b2f(q.x), v1 = b2f(q.y), v2 = b2f(q.z), v3 = b2f(q.w);
  float m = fmaxf(fmaxf(v0, v1), fmaxf(v2, v3));
#pragma unroll
  for (int off = 32; off; off >>= 1) m = fmaxf(m, __shfl_xor(m, off));
  float s = __expf(v0 - m) + __expf(v1 - m) + __expf(v2 - m) + __expf(v3 - m);
#pragma unroll
  for (int off = 32; off; off >>= 1) s += __shfl_xor(s, off);
  if (l == 0) { rm[r] = m; ri[r] = 1.f / s; }
}

__global__ void colstats(const u16* __restrict__ X, float* __restrict__ cm,
                         float* __restrict__ ci) {
  int b = blockIdx.x, j0 = blockIdx.y * 16;
  int tid = threadIdx.x, jj = tid & 15, iq = tid >> 4;
  const u16* base = X + (long long)b * 65536;
  float v[16];
  float m = -1e30f;
#pragma unroll
  for (int ch = 0; ch < 16; ++ch) {
    v[ch] = b2f(base[(ch * 16 + iq) * 256 + j0 + jj]);
    m = fmaxf(m, v[ch]);
  }
  __shared__ float red[256];
  red[tid] = m; __syncthreads();
#pragma unroll
  for (int off = 128; off >= 16; off >>= 1) {
    if (tid < off) red[tid] = fmaxf(red[tid], red[tid + off]);
    __syncthreads();
  }
  float mm = red[jj]; __syncthreads();
  float s = 0.f;
#pragma unroll
  for (int ch = 0; ch < 16; ++ch) s += __expf(v[ch] - mm);
  red[tid] = s; __syncthreads();
#pragma unroll
  for (int off = 128; off >= 16; off >>= 1) {
    if (tid < off) red[tid] += red[tid + off];
    __syncthreads();
  }
  if (tid < 16) { cm[b * 256 + j0 + tid] = mm; ci[b * 256 + j0 + tid] = 1.f / red[tid]; }
}

// ---------------- PV GEMMs: on-the-fly softmax A, transpose-staged V from hid ------
// TRANSA=0: C[i][h] = sum_j exp(X[i][j]-rm[i])*ri[i] * Hh[j][h]
// TRANSA=1: C[j][h] = sum_i exp(X[i][j]-cm[j])*ci[j] * Hp[i][h]
// pmax[(z*4+blockIdx.x)*256 + col] = max over the tile's 64 rows

template <int TRANSA>
__global__ __launch_bounds__(256, 2) void gemm_pv(
    const u16* __restrict__ X, const u16* __restrict__ H,
    const float* __restrict__ sm, const float* __restrict__ sinv,
    float* __restrict__ pmax) {
  __shared__ __align__(16) u16 La[64 * 40];
  __shared__ __align__(16) u16 Lb[64 * 40];
  __shared__ float red[8][64];
  const int z = blockIdx.z;
  const u16* Xz = X + (long long)z * 65536;
  const u16* B = H + (long long)(TRANSA ? z : z + 256) * SS * KP;
  const int m0 = blockIdx.x * 64, n0 = blockIdx.y * 64;
  const int tid = threadIdx.x, l = tid & 63, w = tid >> 6;
  const int wr = w >> 1, wc = w & 1;
  const int sr = tid >> 2, sc = (tid & 3) * 8;
  const int sr2 = tid >> 3, sc2 = (tid & 7) * 8;

  float m_s0 = 0.f, i_s0 = 0.f;
  float mj[8], ij[8];
  if (TRANSA == 0) {
    m_s0 = sm[z * 256 + m0 + sr];
    i_s0 = sinv[z * 256 + m0 + sr];
  } else {
#pragma unroll
    for (int e = 0; e < 8; ++e) {
      mj[e] = sm[z * 256 + m0 + sc2 + e];
      ij[e] = sinv[z * 256 + m0 + sc2 + e];
    }
  }

  float4v acc[2][2] = {};
  for (int k0 = 0; k0 < SS; k0 += 32) {
    union { uint4v v; u16 s[8]; } ua, ub;
    if (TRANSA == 0)
      ua.v = *(const uint4v*)&Xz[(m0 + sr) * SS + k0 + sc];
    else
      ua.v = *(const uint4v*)&Xz[(k0 + sr2) * SS + m0 + sc2];
    ub.v = *(const uint4v*)&B[(long long)(k0 + sr2) * KP + n0 + sc2];
    __syncthreads();
    if (TRANSA == 0) {
      u16 pa[8];
#pragma unroll
      for (int e = 0; e < 8; ++e)
        pa[e] = f2b(__expf(b2f(ua.s[e]) - m_s0) * i_s0);
      uint4v pk;
      pk.x = (unsigned)pa[0] | ((unsigned)pa[1] << 16);
      pk.y = (unsigned)pa[2] | ((unsigned)pa[3] << 16);
      pk.z = (unsigned)pa[4] | ((unsigned)pa[5] << 16);
      pk.w = (unsigned)pa[6] | ((unsigned)pa[7] << 16);
      *(uint4v*)&La[sr * 40 + sc] = pk;
    } else {
#pragma unroll
      for (int e = 0; e < 8; ++e)
        La[(sc2 + e) * 40 + sr2] = f2b(__expf(b2f(ua.s[e]) - mj[e]) * ij[e]);
    }
    // V staged transposed: Lb[hcol][k] from hid rows (k) x hcols
#pragma unroll
    for (int e = 0; e < 8; ++e)
      Lb[(sc2 + e) * 40 + sr2] = (n0 + sc2 + e < KP) ? ub.s[e] : (u16)0;
    __syncthreads();
    bf16x8 af[2], bfr[2];
#pragma unroll
    for (int mt = 0; mt < 2; ++mt)
      af[mt] = *(const bf16x8*)&La[(wr * 32 + mt * 16 + (l & 15)) * 40 + (l >> 4) * 8];
#pragma unroll
    for (int nt = 0; nt < 2; ++nt)
      bfr[nt] = *(const bf16x8*)&Lb[(wc * 32 + nt * 16 + (l & 15)) * 40 + (l >> 4) * 8];
#pragma unroll
    for (int mt = 0; mt < 2; ++mt)
#pragma unroll
      for (int nt = 0; nt < 2; ++nt)
        acc[mt][nt] = __builtin_amdgcn_mfma_f32_16x16x32_bf16(af[mt], bfr[nt], acc[mt][nt], 0, 0, 0);
  }
  // fused max over the 64 tile rows
#pragma unroll
  for (int nt = 0; nt < 2; ++nt) {
    float v = -1e30f;
#pragma unroll
    for (int mt = 0; mt < 2; ++mt)
#pragma unroll
      for (int j = 0; j < 4; ++j) v = fmaxf(v, acc[mt][nt][j]);
    red[wr * 4 + (l >> 4)][wc * 32 + nt * 16 + (l & 15)] = v;
  }
  __syncthreads();
  if (tid < 64) {
    float m = red[0][tid];
#pragma unroll
    for (int g = 1; g < 8; ++g) m = fmaxf(m, red[g][tid]);
    pmax[((long long)z * 4 + blockIdx.x) * 256 + n0 + tid] = m;
  }
}

__global__ void maxfinal(const float* __restrict__ p1, const float* __restrict__ p2,
                         float* __restrict__ hq, float* __restrict__ hs) {
  int b = blockIdx.x, h = threadIdx.x;
  if (h < HID) {
    float m1 = -1e30f, m2 = -1e30f;
#pragma unroll
    for (int x = 0; x < 4; ++x) {
      m1 = fmaxf(m1, p1[(b * 4 + x) * 256 + h]);
      m2 = fmaxf(m2, p2[(b * 4 + x) * 256 + h]);
    }
    hq[b * HID + h] = m1;
    hs[b * HID + h] = m2;
  }
}

// ---------------- head: feat -> logits -> log_softmax (f32 out) ----------------

__global__ void final_k(const float* __restrict__ hq, const float* __restrict__ hs,
                        const float* __restrict__ Wl, const float* __restrict__ bl,
                        float* __restrict__ out) {
  int b = blockIdx.x, t = threadIdx.x;
  float a0 = 0.f, a1v = 0.f, a2v = 0.f;
  for (int hp = t; hp < 800; hp += 256) {
    int part = hp / 200, u = hp - part * 200;
    float q = hq[b * HID + u], s = hs[b * HID + u];
    float f = (part == 0) ? q : (part == 1) ? s : (part == 2) ? (q - s) : (q * s);
    a0 += f * Wl[hp]; a1v += f * Wl[800 + hp]; a2v += f * Wl[1600 + hp];
  }
#pragma unroll
  for (int off = 32; off; off >>= 1) {
    a0 += __shfl_xor(a0, off); a1v += __shfl_xor(a1v, off); a2v += __shfl_xor(a2v, off);
  }
  __shared__ float rr[12];
  int w = t >> 6;
  if ((t & 63) == 0) { rr[w] = a0; rr[4 + w] = a1v; rr[8 + w] = a2v; }
  __syncthreads();
  if (t == 0) {
    float l0 = rr[0] + rr[1] + rr[2] + rr[3] + bl[0];
    float l1 = rr[4] + rr[5] + rr[6] + rr[7] + bl[1];
    float l2 = rr[8] + rr[9] + rr[10] + rr[11] + bl[2];
    float mm = fmaxf(l0, fmaxf(l1, l2));
    float lse = mm + __logf(__expf(l0 - mm) + __expf(l1 - mm) + __expf(l2 - mm));
    out[b * 3 + 0] = l0 - lse;
    out[b * 3 + 1] = l1 - lse;
    out[b * 3 + 2] = l2 - lse;
  }
}

// ---------------- host ----------------

extern "C" void kernel_launch(void* const* d_in, const int* in_sizes, int n_in,
                              void* d_out, int out_size, void* d_ws, size_t ws_size,
                              hipStream_t stream) {
  const int* premise = (const int*)d_in[0];
  const int* hypothesis = (const int*)d_in[1];
  const float* emb = (const float*)d_in[2];
  const float* W_ih = (const float*)d_in[3];
  const float* W_hh = (const float*)d_in[4];
  const float* b_ih = (const float*)d_in[5];
  const float* b_hh = (const float*)d_in[6];
  const float* W_last = (const float*)d_in[7];
  const float* b_last = (const float*)d_in[8];
  float* out = (float*)d_out;

  char* ws = (char*)d_ws;
  // layout (bytes), peak = 118,664,064 (~113 MB)
  const size_t O_hid  = 0;          // [512][256][224] bf16 = 58,720,256
  const size_t O_embB = 0;          // [36928][320] bf16 (dead before lstm writes hid)
  const size_t O_E2   = 58720256;   // [36906][800] bf16 = 59,049,600 (dead after LSTM)
  const size_t O_X    = 58720256;   // [256][256][256] bf16 = 33,554,432 (overlays dead E2)
  const size_t O_rm   = 92274688;   // 65536 f32 (overlays dead E2 tail)
  const size_t O_ri   = 92536832;
  const size_t O_cm   = 92798976;
  const size_t O_ci   = 93061120;
  const size_t O_p1   = 93323264;   // [256][4][256] f32
  const size_t O_p2   = 94371840;
  const size_t O_hq   = 95420416;   // [256][200] f32
  const size_t O_hs   = 95625216;
  const size_t O_whh  = 117769856;  // [800][224] bf16 (live through LSTM, after E2 end)
  const size_t O_wih  = 118128256;  // [832][320] bf16
  const size_t O_bias = 118660736;  // 832 f32 -> end 118,664,064

  u16* hid  = (u16*)(ws + O_hid);
  u16* embB = (u16*)(ws + O_embB);
  u16* E2   = (u16*)(ws + O_E2);
  u16* X    = (u16*)(ws + O_X);
  float* rm = (float*)(ws + O_rm);
  float* ri = (float*)(ws + O_ri);
  float* cm = (float*)(ws + O_cm);
  float* ci = (float*)(ws + O_ci);
  float* p1 = (float*)(ws + O_p1);
  float* p2 = (float*)(ws + O_p2);
  float* hq = (float*)(ws + O_hq);
  float* hs = (float*)(ws + O_hs);
  u16* whhB = (u16*)(ws + O_whh);
  u16* wihB = (u16*)(ws + O_wih);
  float* biasP = (float*)(ws + O_bias);

  conv_emb<<<4096, 256, 0, stream>>>(emb, embB);
  conv_pack<<<(R0N + R1N + R2N + 255) / 256, 256, 0, stream>>>(
      W_ih, W_hh, b_ih, b_hh, wihB, whhB, biasP);

  gemm_e2<<<dim3(VPAD / 64, NGP / 64), 256, 0, stream>>>(embB, wihB, E2, biasP);

  lstm_kernel<<<128, 512, 0, stream>>>(premise, hypothesis, E2, whhB, hid);

  gemm_attn<<<dim3(4, 4, 256), 256, 0, stream>>>(hid, X);

  rowstats<<<16384, 256, 0, stream>>>(X, rm, ri);
  colstats<<<dim3(256, 16), 256, 0, stream>>>(X, cm, ci);

  gemm_pv<0><<<dim3(4, 4, 256), 256, 0, stream>>>(X, hid, rm, ri, p1);
  gemm_pv<1><<<dim3(4, 4, 256), 256, 0, stream>>>(X, hid, cm, ci, p2);

  maxfinal<<<256, 256, 0, stream>>>(p1, p2, hq, hs);
  final_k<<<256, 256, 0, stream>>>(hq, hs, W_last, b_last, out);
}

// Round 17
// 661.904 us; speedup vs baseline: 1.6705x; 1.1303x over previous
//
#include <hip/hip_runtime.h>

typedef unsigned short u16;
typedef __attribute__((ext_vector_type(8))) __bf16 bf16x8;
typedef __attribute__((ext_vector_type(4))) float float4v;
typedef __attribute__((ext_vector_type(4))) u16 ushort4v;
typedef __attribute__((ext_vector_type(4))) unsigned int uint4v;

#define VOCAB 36906
#define VPAD  36928   // 577*64
#define WDP   320     // K-pad of 300 for emb GEMM
#define HID   200
#define NG    800     // 4H
#define NGP   832     // 13*64
#define KP    224     // 7*32 (H padded)
#define SS    256
#define ROWS  2       // LSTM rows per block (256 blocks -> all CUs)
#define HS    232     // hbuf row stride (u16)
#define GSF   804     // gbufF row stride (f32)
#define WLS   228     // wlds row stride (u16)
#define NREG  5       // AGPR-resident W_hh tiles per wave (tiles w+8i -> 0..39)
#define NLDS  10      // LDS-resident tiles 40..49

__device__ __forceinline__ float b2f(u16 u) {
  union { unsigned int i; float f; } c; c.i = ((unsigned int)u) << 16; return c.f;
}
__device__ __forceinline__ u16 f2b(float f) {
  union { float f; unsigned int i; } c; c.f = f;
  unsigned int u = c.i;
  u += 0x7fffu + ((u >> 16) & 1u);
  return (u16)(u >> 16);
}
__device__ __forceinline__ float sigm(float x) { return 1.f / (1.f + __expf(-x)); }
__device__ __forceinline__ float tanh_f(float x) {
  float e = __expf(2.f * x);
  return 1.f - 2.f / (e + 1.f);
}

// ---------------- packing ----------------

__global__ void conv_emb(const float* __restrict__ emb, u16* __restrict__ out) {
  for (long long idx = (long long)blockIdx.x * 256 + threadIdx.x;
       idx < (long long)VPAD * WDP; idx += (long long)gridDim.x * 256) {
    int v = (int)(idx / WDP), k = (int)(idx % WDP);
    float val = (v < VOCAB && k < 300) ? emb[(long long)v * 300 + k] : 0.f;
    out[idx] = f2b(val);
  }
}

// W_ih (permuted n'=4j+gate, K-pad 320) + W_hh (permuted, K-pad 224) + bias, fused
#define R0N (NGP * WDP)
#define R1N (NG * KP)
#define R2N (NGP)

__global__ void conv_pack(const float* __restrict__ Wih, const float* __restrict__ Whh,
                          const float* __restrict__ bi, const float* __restrict__ bh,
                          u16* __restrict__ wihB, u16* __restrict__ whhB,
                          float* __restrict__ biasP) {
  int idx = blockIdx.x * 256 + threadIdx.x;
  if (idx < R0N) {
    int n = idx / WDP, k = idx % WDP;
    float v = 0.f;
    if (n < NG && k < 300) { int gt = n & 3, j = n >> 2; v = Wih[(gt * HID + j) * 300 + k]; }
    wihB[idx] = f2b(v);
  } else if (idx < R0N + R1N) {
    int r = idx - R0N;
    int n = r / KP, k = r % KP;
    int gt = n & 3, j = n >> 2;
    float v = (k < HID) ? Whh[(gt * HID + j) * HID + k] : 0.f;
    whhB[r] = f2b(v);
  } else if (idx < R0N + R1N + R2N) {
    int n = idx - R0N - R1N;
    float v = 0.f;
    if (n < NG) { int gt = n & 3, j = n >> 2; v = bi[gt * HID + j] + bh[gt * HID + j]; }
    biasP[n] = v;
  }
}

// ---------------- E2 = emb @ W_ih'^T + bias  (NT GEMM, bf16 A) ----------------

__global__ __launch_bounds__(256, 2) void gemm_e2(
    const u16* __restrict__ A, const u16* __restrict__ B, u16* __restrict__ C,
    const float* __restrict__ bias) {
  __shared__ __align__(16) u16 La[64 * 40];
  __shared__ __align__(16) u16 Lb[64 * 40];
  const int m0 = blockIdx.x * 64, n0 = blockIdx.y * 64;
  const int tid = threadIdx.x, l = tid & 63, w = tid >> 6;
  const int wr = w >> 1, wc = w & 1;
  const int sr = tid >> 2, sc = (tid & 3) * 8;
  float4v acc[2][2] = {};
  for (int k0 = 0; k0 < WDP; k0 += 32) {
    uint4v qa = *(const uint4v*)&A[(long long)(m0 + sr) * WDP + k0 + sc];
    uint4v qb = *(const uint4v*)&B[(long long)(n0 + sr) * WDP + k0 + sc];
    __syncthreads();
    *(uint4v*)&La[sr * 40 + sc] = qa;
    *(uint4v*)&Lb[sr * 40 + sc] = qb;
    __syncthreads();
    bf16x8 af[2], bfr[2];
#pragma unroll
    for (int mt = 0; mt < 2; ++mt)
      af[mt] = *(const bf16x8*)&La[(wr * 32 + mt * 16 + (l & 15)) * 40 + (l >> 4) * 8];
#pragma unroll
    for (int nt = 0; nt < 2; ++nt)
      bfr[nt] = *(const bf16x8*)&Lb[(wc * 32 + nt * 16 + (l & 15)) * 40 + (l >> 4) * 8];
#pragma unroll
    for (int mt = 0; mt < 2; ++mt)
#pragma unroll
      for (int nt = 0; nt < 2; ++nt)
        acc[mt][nt] = __builtin_amdgcn_mfma_f32_16x16x32_bf16(af[mt], bfr[nt], acc[mt][nt], 0, 0, 0);
  }
#pragma unroll
  for (int mt = 0; mt < 2; ++mt)
#pragma unroll
    for (int nt = 0; nt < 2; ++nt)
#pragma unroll
      for (int j = 0; j < 4; ++j) {
        int row = m0 + wr * 32 + mt * 16 + (l >> 4) * 4 + j;
        int col = n0 + wc * 32 + nt * 16 + (l & 15);
        if (row < VOCAB && col < NG)
          C[(long long)row * NG + col] = f2b(acc[mt][nt][j] + bias[col]);
      }
}

// ---------------- LSTM: 256 blocks x 2 rows x 512 threads (8 waves) ----------------
// (R13 structure, ROWS=2) W_hh: 40 tiles AGPR (5/wave, tiles w+8i) + 10 LDS tiles.
// Swapped-operand MFMA -> C[unit][row]; gates cross LDS once as f32 b128 (gbufF).
// E2 register-dbuf added in phase B (single 400-thread iteration).
// hid: [512 r][256 t][224 h] bf16.

__global__ __launch_bounds__(512, 2) void lstm_kernel(
    const int* __restrict__ premise, const int* __restrict__ hypothesis,
    const u16* __restrict__ E2, const u16* __restrict__ Whh,
    u16* __restrict__ hid) {
  __shared__ u16 tok[ROWS * 256];                     //   1.0 KB
  __shared__ __align__(16) u16 hbuf[16 * HS];         //   7.3 KB
  __shared__ __align__(16) float gbufF[16 * GSF];     //  50.3 KB
  __shared__ __align__(16) u16 wlds[NLDS * 16 * WLS]; //  71.3 KB -> ~130 KB total
  const int tid = threadIdx.x;
  const int l = tid & 63, w = tid >> 6;
  const int r0 = blockIdx.x * ROWS;

  for (int idx = tid; idx < ROWS * 256; idx += 512) {
    int mm = idx >> 8, tt = idx & 255;
    int row = r0 + mm;
    const int* seq = (row < 256) ? premise : hypothesis;
    tok[idx] = (u16)seq[(row & 255) * 256 + tt];
  }
  for (int idx = tid; idx < 16 * HS; idx += 512) hbuf[idx] = 0;
  // LDS-resident W_hh tiles 40..49
  for (int idx = tid; idx < NLDS * 16 * KP; idx += 512) {
    int slot = idx / (16 * KP), rem = idx % (16 * KP);
    int r = rem / KP, k = rem % KP;
    wlds[(slot * 16 + r) * WLS + k] = Whh[((40 + slot) * 16 + r) * KP + k];
  }

  // AGPR-resident W_hh: wave w owns tiles w+8i, i<NREG (0..39)
  uint4v wf[NREG][7];
#pragma unroll
  for (int i = 0; i < NREG; ++i) {
    int nt = w + 8 * i;
#pragma unroll
    for (int kf = 0; kf < 7; ++kf)
      wf[i][kf] = *(const uint4v*)&Whh[(nt * 16 + (l & 15)) * KP + kf * 32 + (l >> 4) * 8];
  }
#pragma unroll
  for (int i = 0; i < NREG; ++i)
#pragma unroll
    for (int kf = 0; kf < 7; ++kf)
      asm volatile("" : "+a"(wf[i][kf]));

  float cst = 0.f;

  // preload E2(t=0): thread owns quad u = tid (u < 400): (m=u/200, j=u%200)
  ushort4v ev = ushort4v{0, 0, 0, 0};
  {
    int u = tid;
    if (u < ROWS * 200) {
      int m = u / 200, j = u - m * 200;
      int tk = tok[m * 256];
      ev = *(const ushort4v*)&E2[(long long)tk * NG + 4 * j];
    }
  }
  __syncthreads();

  for (int t = 0; t < SS; ++t) {
    // coalesced hid write of h(t-1)
    if (t > 0) {
      const unsigned* hb32 = (const unsigned*)hbuf;
      unsigned* hid32 = (unsigned*)hid;
      if (tid < ROWS * 112) {
        int m2 = tid / 112, c = tid - 112 * m2;
        hid32[((long long)(r0 + m2) * SS + (t - 1)) * 112 + c] = hb32[m2 * 116 + c];
      }
    }

    // prefetch E2 for t+1
    int t2 = (t < SS - 1) ? t + 1 : t;
    ushort4v evn = ushort4v{0, 0, 0, 0};
    {
      int u = tid;
      if (u < ROWS * 200) {
        int m = u / 200, j = u - m * 200;
        int tk = tok[m * 256 + t2];
        evn = *(const ushort4v*)&E2[(long long)tk * NG + 4 * j];
      }
    }

    // A-fragments (h(t-1)) from hbuf
    bf16x8 af[7];
#pragma unroll
    for (int kf = 0; kf < 7; ++kf)
      af[kf] = *(const bf16x8*)&hbuf[(l & 15) * HS + kf * 32 + (l >> 4) * 8];

    // ---- phase A: W@h -> gbufF (C[unit'][row]; write b128 per tile) ----
    {
      float4v acc[NREG];
#pragma unroll
      for (int i = 0; i < NREG; ++i) acc[i] = float4v{0.f, 0.f, 0.f, 0.f};
      asm volatile("s_nop 1"
                   : "+v"(acc[0]), "+v"(acc[1]), "+v"(acc[2]), "+v"(acc[3]), "+v"(acc[4]));
#pragma unroll
      for (int kf = 0; kf < 7; ++kf)
#pragma unroll
        for (int i = 0; i < NREG; ++i)
          asm volatile("v_mfma_f32_16x16x32_bf16 %0, %1, %2, %0"
                       : "+v"(acc[i])
                       : "a"(wf[i][kf]), "v"(af[kf]));
      asm volatile("s_nop 7\n\ts_nop 7"
                   : "+v"(acc[0]), "+v"(acc[1]), "+v"(acc[2]), "+v"(acc[3]), "+v"(acc[4]));
#pragma unroll
      for (int i = 0; i < NREG; ++i) {
        int nt = w + 8 * i;
        *(float4v*)&gbufF[(l & 15) * GSF + nt * 16 + (l >> 4) * 4] = acc[i];
      }
    }
    // LDS tiles: slot w (tile 40+w); waves 0,1 also slot 8+w (tiles 48,49)
    {
      float4v a2 = {0.f, 0.f, 0.f, 0.f};
#pragma unroll
      for (int kf = 0; kf < 7; ++kf) {
        bf16x8 bfr = *(const bf16x8*)&wlds[(w * 16 + (l & 15)) * WLS + kf * 32 + (l >> 4) * 8];
        a2 = __builtin_amdgcn_mfma_f32_16x16x32_bf16(bfr, af[kf], a2, 0, 0, 0);
      }
      *(float4v*)&gbufF[(l & 15) * GSF + (40 + w) * 16 + (l >> 4) * 4] = a2;
    }
    if (w < 2) {
      int slot = 8 + w;
      float4v a2 = {0.f, 0.f, 0.f, 0.f};
#pragma unroll
      for (int kf = 0; kf < 7; ++kf) {
        bf16x8 bfr = *(const bf16x8*)&wlds[(slot * 16 + (l & 15)) * WLS + kf * 32 + (l >> 4) * 8];
        a2 = __builtin_amdgcn_mfma_f32_16x16x32_bf16(bfr, af[kf], a2, 0, 0, 0);
      }
      *(float4v*)&gbufF[(l & 15) * GSF + (48 + w) * 16 + (l >> 4) * 4] = a2;
    }
    __syncthreads();

    // ---- phase B: gates = gbufF + E2(reg) -> nonlinearity -> h(t) ----
    {
      int u = tid;
      if (u < ROWS * 200) {
        int m = u / 200, j = u - m * 200;
        float4v gv = *(const float4v*)&gbufF[m * GSF + 4 * j];
        float gi = gv[0] + b2f(ev.x);
        float gf = gv[1] + b2f(ev.y);
        float gg = gv[2] + b2f(ev.z);
        float go = gv[3] + b2f(ev.w);
        float cn = sigm(gf) * cst + sigm(gi) * tanh_f(gg);
        float hn = sigm(go) * tanh_f(cn);
        cst = cn;
        hbuf[m * HS + j] = f2b(hn);
      }
    }
    ev = evn;
    __syncthreads();
  }

  // epilogue: write h(255)
  {
    const unsigned* hb32 = (const unsigned*)hbuf;
    unsigned* hid32 = (unsigned*)hid;
    if (tid < ROWS * 112) {
      int m2 = tid / 112, c = tid - 112 * m2;
      hid32[((long long)(r0 + m2) * SS + (SS - 1)) * 112 + c] = hb32[m2 * 116 + c];
    }
  }
}

// ---------------- attn (NT): X[b][i][j] = sum_h Hp[i][h]*Hh[j][h], bf16 out --------

__global__ __launch_bounds__(256, 2) void gemm_attn(const u16* __restrict__ H,
                                                    u16* __restrict__ X) {
  __shared__ __align__(16) u16 La[64 * 40];
  __shared__ __align__(16) u16 Lb[64 * 40];
  const int z = blockIdx.z;
  const u16* A = H + (long long)z * SS * KP;
  const u16* B = H + (long long)(z + 256) * SS * KP;
  u16* C = X + (long long)z * 65536;
  const int m0 = blockIdx.x * 64, n0 = blockIdx.y * 64;
  const int tid = threadIdx.x, l = tid & 63, w = tid >> 6;
  const int wr = w >> 1, wc = w & 1;
  const int sr = tid >> 2, sc = (tid & 3) * 8;
  float4v acc[2][2] = {};
  for (int k0 = 0; k0 < KP; k0 += 32) {
    uint4v qa = *(const uint4v*)&A[(m0 + sr) * KP + k0 + sc];
    uint4v qb = *(const uint4v*)&B[(n0 + sr) * KP + k0 + sc];
    __syncthreads();
    *(uint4v*)&La[sr * 40 + sc] = qa;
    *(uint4v*)&Lb[sr * 40 + sc] = qb;
    __syncthreads();
    bf16x8 af[2], bfr[2];
#pragma unroll
    for (int mt = 0; mt < 2; ++mt)
      af[mt] = *(const bf16x8*)&La[(wr * 32 + mt * 16 + (l & 15)) * 40 + (l >> 4) * 8];
#pragma unroll
    for (int nt = 0; nt < 2; ++nt)
      bfr[nt] = *(const bf16x8*)&Lb[(wc * 32 + nt * 16 + (l & 15)) * 40 + (l >> 4) * 8];
#pragma unroll
    for (int mt = 0; mt < 2; ++mt)
#pragma unroll
      for (int nt = 0; nt < 2; ++nt)
        acc[mt][nt] = __builtin_amdgcn_mfma_f32_16x16x32_bf16(af[mt], bfr[nt], acc[mt][nt], 0, 0, 0);
  }
#pragma unroll
  for (int mt = 0; mt < 2; ++mt)
#pragma unroll
    for (int nt = 0; nt < 2; ++nt)
#pragma unroll
      for (int j = 0; j < 4; ++j) {
        int row = m0 + wr * 32 + mt * 16 + (l >> 4) * 4 + j;
        int col = n0 + wc * 32 + nt * 16 + (l & 15);
        C[row * SS + col] = f2b(acc[mt][nt][j]);
      }
}

// ---------------- softmax stats ----------------

__global__ void rowstats(const u16* __restrict__ X, float* __restrict__ rm,
                         float* __restrict__ ri) {
  int r = blockIdx.x * 4 + (threadIdx.x >> 6);
  int l = threadIdx.x & 63;
  ushort4v q = *(const ushort4v*)(X + (long long)r * 256 + l * 4);
  float v0 = b2f(q.x), v1 = b2f(q.y), v2 = b2f(q.z), v3 = b2f(q.w);
  float m = fmaxf(fmaxf(v0, v1), fmaxf(v2, v3));
#pragma unroll
  for (int off = 32; off; off >>= 1) m = fmaxf(m, __shfl_xor(m, off));
  float s = __expf(v0 - m) + __expf(v1 - m) + __expf(v2 - m) + __expf(v3 - m);
#pragma unroll
  for (int off = 32; off; off >>= 1) s += __shfl_xor(s, off);
  if (l == 0) { rm[r] = m; ri[r] = 1.f / s; }
}

__global__ void colstats(const u16* __restrict__ X, float* __restrict__ cm,
                         float* __restrict__ ci) {
  int b = blockIdx.x, j0 = blockIdx.y * 16;
  int tid = threadIdx.x, jj = tid & 15, iq = tid >> 4;
  const u16* base = X + (long long)b * 65536;
  float v[16];
  float m = -1e30f;
#pragma unroll
  for (int ch = 0; ch < 16; ++ch) {
    v[ch] = b2f(base[(ch * 16 + iq) * 256 + j0 + jj]);
    m = fmaxf(m, v[ch]);
  }
  __shared__ float red[256];
  red[tid] = m; __syncthreads();
#pragma unroll
  for (int off = 128; off >= 16; off >>= 1) {
    if (tid < off) red[tid] = fmaxf(red[tid], red[tid + off]);
    __syncthreads();
  }
  float mm = red[jj]; __syncthreads();
  float s = 0.f;
#pragma unroll
  for (int ch = 0; ch < 16; ++ch) s += __expf(v[ch] - mm);
  red[tid] = s; __syncthreads();
#pragma unroll
  for (int off = 128; off >= 16; off >>= 1) {
    if (tid < off) red[tid] += red[tid + off];
    __syncthreads();
  }
  if (tid < 16) { cm[b * 256 + j0 + tid] = mm; ci[b * 256 + j0 + tid] = 1.f / red[tid]; }
}

// ---------------- PV GEMMs: on-the-fly softmax A, transpose-staged V from hid ------
// TRANSA=0: C[i][h] = sum_j exp(X[i][j]-rm[i])*ri[i] * Hh[j][h]
// TRANSA=1: C[j][h] = sum_i exp(X[i][j]-cm[j])*ci[j] * Hp[i][h]
// pmax[(z*4+blockIdx.x)*256 + col] = max over the tile's 64 rows

template <int TRANSA>
__global__ __launch_bounds__(256, 2) void gemm_pv(
    const u16* __restrict__ X, const u16* __restrict__ H,
    const float* __restrict__ sm, const float* __restrict__ sinv,
    float* __restrict__ pmax) {
  __shared__ __align__(16) u16 La[64 * 40];
  __shared__ __align__(16) u16 Lb[64 * 40];
  __shared__ float red[8][64];
  const int z = blockIdx.z;
  const u16* Xz = X + (long long)z * 65536;
  const u16* B = H + (long long)(TRANSA ? z : z + 256) * SS * KP;
  const int m0 = blockIdx.x * 64, n0 = blockIdx.y * 64;
  const int tid = threadIdx.x, l = tid & 63, w = tid >> 6;
  const int wr = w >> 1, wc = w & 1;
  const int sr = tid >> 2, sc = (tid & 3) * 8;
  const int sr2 = tid >> 3, sc2 = (tid & 7) * 8;

  float m_s0 = 0.f, i_s0 = 0.f;
  float mj[8], ij[8];
  if (TRANSA == 0) {
    m_s0 = sm[z * 256 + m0 + sr];
    i_s0 = sinv[z * 256 + m0 + sr];
  } else {
#pragma unroll
    for (int e = 0; e < 8; ++e) {
      mj[e] = sm[z * 256 + m0 + sc2 + e];
      ij[e] = sinv[z * 256 + m0 + sc2 + e];
    }
  }

  float4v acc[2][2] = {};
  for (int k0 = 0; k0 < SS; k0 += 32) {
    union { uint4v v; u16 s[8]; } ua, ub;
    if (TRANSA == 0)
      ua.v = *(const uint4v*)&Xz[(m0 + sr) * SS + k0 + sc];
    else
      ua.v = *(const uint4v*)&Xz[(k0 + sr2) * SS + m0 + sc2];
    ub.v = *(const uint4v*)&B[(long long)(k0 + sr2) * KP + n0 + sc2];
    __syncthreads();
    if (TRANSA == 0) {
      u16 pa[8];
#pragma unroll
      for (int e = 0; e < 8; ++e)
        pa[e] = f2b(__expf(b2f(ua.s[e]) - m_s0) * i_s0);
      uint4v pk;
      pk.x = (unsigned)pa[0] | ((unsigned)pa[1] << 16);
      pk.y = (unsigned)pa[2] | ((unsigned)pa[3] << 16);
      pk.z = (unsigned)pa[4] | ((unsigned)pa[5] << 16);
      pk.w = (unsigned)pa[6] | ((unsigned)pa[7] << 16);
      *(uint4v*)&La[sr * 40 + sc] = pk;
    } else {
#pragma unroll
      for (int e = 0; e < 8; ++e)
        La[(sc2 + e) * 40 + sr2] = f2b(__expf(b2f(ua.s[e]) - mj[e]) * ij[e]);
    }
    // V staged transposed: Lb[hcol][k] from hid rows (k) x hcols
#pragma unroll
    for (int e = 0; e < 8; ++e)
      Lb[(sc2 + e) * 40 + sr2] = (n0 + sc2 + e < KP) ? ub.s[e] : (u16)0;
    __syncthreads();
    bf16x8 af[2], bfr[2];
#pragma unroll
    for (int mt = 0; mt < 2; ++mt)
      af[mt] = *(const bf16x8*)&La[(wr * 32 + mt * 16 + (l & 15)) * 40 + (l >> 4) * 8];
#pragma unroll
    for (int nt = 0; nt < 2; ++nt)
      bfr[nt] = *(const bf16x8*)&Lb[(wc * 32 + nt * 16 + (l & 15)) * 40 + (l >> 4) * 8];
#pragma unroll
    for (int mt = 0; mt < 2; ++mt)
#pragma unroll
      for (int nt = 0; nt < 2; ++nt)
        acc[mt][nt] = __builtin_amdgcn_mfma_f32_16x16x32_bf16(af[mt], bfr[nt], acc[mt][nt], 0, 0, 0);
  }
  // fused max over the 64 tile rows
#pragma unroll
  for (int nt = 0; nt < 2; ++nt) {
    float v = -1e30f;
#pragma unroll
    for (int mt = 0; mt < 2; ++mt)
#pragma unroll
      for (int j = 0; j < 4; ++j) v = fmaxf(v, acc[mt][nt][j]);
    red[wr * 4 + (l >> 4)][wc * 32 + nt * 16 + (l & 15)] = v;
  }
  __syncthreads();
  if (tid < 64) {
    float m = red[0][tid];
#pragma unroll
    for (int g = 1; g < 8; ++g) m = fmaxf(m, red[g][tid]);
    pmax[((long long)z * 4 + blockIdx.x) * 256 + n0 + tid] = m;
  }
}

__global__ void maxfinal(const float* __restrict__ p1, const float* __restrict__ p2,
                         float* __restrict__ hq, float* __restrict__ hs) {
  int b = blockIdx.x, h = threadIdx.x;
  if (h < HID) {
    float m1 = -1e30f, m2 = -1e30f;
#pragma unroll
    for (int x = 0; x < 4; ++x) {
      m1 = fmaxf(m1, p1[(b * 4 + x) * 256 + h]);
      m2 = fmaxf(m2, p2[(b * 4 + x) * 256 + h]);
    }
    hq[b * HID + h] = m1;
    hs[b * HID + h] = m2;
  }
}

// ---------------- head: feat -> logits -> log_softmax (f32 out) ----------------

__global__ void final_k(const float* __restrict__ hq, const float* __restrict__ hs,
                        const float* __restrict__ Wl, const float* __restrict__ bl,
                        float* __restrict__ out) {
  int b = blockIdx.x, t = threadIdx.x;
  float a0 = 0.f, a1v = 0.f, a2v = 0.f;
  for (int hp = t; hp < 800; hp += 256) {
    int part = hp / 200, u = hp - part * 200;
    float q = hq[b * HID + u], s = hs[b * HID + u];
    float f = (part == 0) ? q : (part == 1) ? s : (part == 2) ? (q - s) : (q * s);
    a0 += f * Wl[hp]; a1v += f * Wl[800 + hp]; a2v += f * Wl[1600 + hp];
  }
#pragma unroll
  for (int off = 32; off; off >>= 1) {
    a0 += __shfl_xor(a0, off); a1v += __shfl_xor(a1v, off); a2v += __shfl_xor(a2v, off);
  }
  __shared__ float rr[12];
  int w = t >> 6;
  if ((t & 63) == 0) { rr[w] = a0; rr[4 + w] = a1v; rr[8 + w] = a2v; }
  __syncthreads();
  if (t == 0) {
    float l0 = rr[0] + rr[1] + rr[2] + rr[3] + bl[0];
    float l1 = rr[4] + rr[5] + rr[6] + rr[7] + bl[1];
    float l2 = rr[8] + rr[9] + rr[10] + rr[11] + bl[2];
    float mm = fmaxf(l0, fmaxf(l1, l2));
    float lse = mm + __logf(__expf(l0 - mm) + __expf(l1 - mm) + __expf(l2 - mm));
    out[b * 3 + 0] = l0 - lse;
    out[b * 3 + 1] = l1 - lse;
    out[b * 3 + 2] = l2 - lse;
  }
}

// ---------------- host ----------------

extern "C" void kernel_launch(void* const* d_in, const int* in_sizes, int n_in,
                              void* d_out, int out_size, void* d_ws, size_t ws_size,
                              hipStream_t stream) {
  const int* premise = (const int*)d_in[0];
  const int* hypothesis = (const int*)d_in[1];
  const float* emb = (const float*)d_in[2];
  const float* W_ih = (const float*)d_in[3];
  const float* W_hh = (const float*)d_in[4];
  const float* b_ih = (const float*)d_in[5];
  const float* b_hh = (const float*)d_in[6];
  const float* W_last = (const float*)d_in[7];
  const float* b_last = (const float*)d_in[8];
  float* out = (float*)d_out;

  char* ws = (char*)d_ws;
  // layout (bytes), peak = 118,664,064 (~113 MB)
  const size_t O_hid  = 0;          // [512][256][224] bf16 = 58,720,256
  const size_t O_embB = 0;          // [36928][320] bf16 (dead before lstm writes hid)
  const size_t O_E2   = 58720256;   // [36906][800] bf16 = 59,049,600 (dead after LSTM)
  const size_t O_X    = 58720256;   // [256][256][256] bf16 = 33,554,432 (overlays dead E2)
  const size_t O_rm   = 92274688;   // 65536 f32 (overlays dead E2 tail)
  const size_t O_ri   = 92536832;
  const size_t O_cm   = 92798976;
  const size_t O_ci   = 93061120;
  const size_t O_p1   = 93323264;   // [256][4][256] f32
  const size_t O_p2   = 94371840;
  const size_t O_hq   = 95420416;   // [256][200] f32
  const size_t O_hs   = 95625216;
  const size_t O_whh  = 117769856;  // [800][224] bf16 (live through LSTM, after E2 end)
  const size_t O_wih  = 118128256;  // [832][320] bf16
  const size_t O_bias = 118660736;  // 832 f32 -> end 118,664,064

  u16* hid  = (u16*)(ws + O_hid);
  u16* embB = (u16*)(ws + O_embB);
  u16* E2   = (u16*)(ws + O_E2);
  u16* X    = (u16*)(ws + O_X);
  float* rm = (float*)(ws + O_rm);
  float* ri = (float*)(ws + O_ri);
  float* cm = (float*)(ws + O_cm);
  float* ci = (float*)(ws + O_ci);
  float* p1 = (float*)(ws + O_p1);
  float* p2 = (float*)(ws + O_p2);
  float* hq = (float*)(ws + O_hq);
  float* hs = (float*)(ws + O_hs);
  u16* whhB = (u16*)(ws + O_whh);
  u16* wihB = (u16*)(ws + O_wih);
  float* biasP = (float*)(ws + O_bias);

  conv_emb<<<4096, 256, 0, stream>>>(emb, embB);
  conv_pack<<<(R0N + R1N + R2N + 255) / 256, 256, 0, stream>>>(
      W_ih, W_hh, b_ih, b_hh, wihB, whhB, biasP);

  gemm_e2<<<dim3(VPAD / 64, NGP / 64), 256, 0, stream>>>(embB, wihB, E2, biasP);

  lstm_kernel<<<256, 512, 0, stream>>>(premise, hypothesis, E2, whhB, hid);

  gemm_attn<<<dim3(4, 4, 256), 256, 0, stream>>>(hid, X);

  rowstats<<<16384, 256, 0, stream>>>(X, rm, ri);
  colstats<<<dim3(256, 16), 256, 0, stream>>>(X, cm, ci);

  gemm_pv<0><<<dim3(4, 4, 256), 256, 0, stream>>>(X, hid, rm, ri, p1);
  gemm_pv<1><<<dim3(4, 4, 256), 256, 0, stream>>>(X, hid, cm, ci, p2);

  maxfinal<<<256, 256, 0, stream>>>(p1, p2, hq, hs);
  final_k<<<256, 256, 0, stream>>>(hq, hs, W_last, b_last, out);
}